// Round 1
// baseline (10461.110 us; speedup 1.0000x reference)
//
#include <hip/hip_runtime.h>

// ---------------- constants ----------------
constexpr int BATCH = 8;
constexpr int NTOK  = 4097;   // 1 cls + 4096 tokens
constexpr int NP    = 4352;   // padded seq len (multiple of 256)
constexpr int PADR  = 255;    // zero rows prepended
constexpr int EMBD  = 512;
constexpr int NH    = 4;
constexpr int DHD   = 128;
constexpr int LMK   = 256;    // landmarks M
constexpr int LSUB  = 17;     // NP / LMK
constexpr float SCALE_F = 0.08838834764831845f; // 128^-0.5

// ---------------- block reductions (blockDim == 256) ----------------
__device__ __forceinline__ float block_sum256(float v) {
    __shared__ float tmp[4];
    __syncthreads();
#pragma unroll
    for (int off = 32; off > 0; off >>= 1) v += __shfl_down(v, off, 64);
    int t = threadIdx.x;
    if ((t & 63) == 0) tmp[t >> 6] = v;
    __syncthreads();
    return tmp[0] + tmp[1] + tmp[2] + tmp[3];
}

__device__ __forceinline__ float block_max256(float v) {
    __shared__ float tmp[4];
    __syncthreads();
#pragma unroll
    for (int off = 32; off > 0; off >>= 1) v = fmaxf(v, __shfl_down(v, off, 64));
    int t = threadIdx.x;
    if ((t & 63) == 0) tmp[t >> 6] = v;
    __syncthreads();
    return fmaxf(fmaxf(tmp[0], tmp[1]), fmaxf(tmp[2], tmp[3]));
}

// ---------------- generic batched fp32 GEMM ----------------
// C[bz][m][n] = alpha * sum_k A[bz][m][k] * B[bz][k][n] (+bias[n]) (+= if accum)
// A addr: Abase(bz) + (m+Arow)*Am + k          (k-stride always 1)
// B addr: Bbase(bz) + k*Bk + n*Bn              (either Bn==1 or Bk==1)
// C addr: Cbase(bz) + (m+Crow)*Cm + n
// base(bz) = ptr + (bz/div)*s1 + (bz%div)*s2
struct GemmP {
    const float* A; const float* B; float* C; const float* bias;
    long long As1, As2, Bs1, Bs2, Cs1, Cs2;
    int Adiv, Bdiv, Cdiv;
    int Am, Bk, Bn, Cm, Arow, Crow;
    int M, N, K, nb;
    float alpha; int accum;
};

__global__ __launch_bounds__(256) void gemm_k(GemmP p) {
    __shared__ float As[16][64];
    __shared__ float Bs[16][64];
    const int bz = blockIdx.z;
    const float* Ab = p.A + (long long)(bz / p.Adiv) * p.As1 + (long long)(bz % p.Adiv) * p.As2;
    const float* Bb = p.B + (long long)(bz / p.Bdiv) * p.Bs1 + (long long)(bz % p.Bdiv) * p.Bs2;
    float*       Cb = p.C + (long long)(bz / p.Cdiv) * p.Cs1 + (long long)(bz % p.Cdiv) * p.Cs2;
    const int m0 = blockIdx.y * 64, n0 = blockIdx.x * 64;
    const int t = threadIdx.x;
    const int tm = (t >> 4) << 2, tn = (t & 15) << 2;
    const int ar = t >> 2, ak = (t & 3) << 2;
    float acc[4][4] = {{0.f}};

    for (int k0 = 0; k0 < p.K; k0 += 16) {
        float4 av = make_float4(0.f, 0.f, 0.f, 0.f);
        if (m0 + ar < p.M)
            av = *(const float4*)(Ab + (long long)(m0 + ar + p.Arow) * p.Am + (k0 + ak));
        As[ak][ar] = av.x; As[ak + 1][ar] = av.y; As[ak + 2][ar] = av.z; As[ak + 3][ar] = av.w;
        if (p.Bn == 1) {
            const int bk = t >> 4, bn = (t & 15) << 2;
            float4 bv = *(const float4*)(Bb + (long long)(k0 + bk) * p.Bk + (n0 + bn));
            *(float4*)&Bs[bk][bn] = bv;
        } else { // Bk == 1
            const int bn = t >> 2, bk = (t & 3) << 2;
            float4 bv = *(const float4*)(Bb + (long long)(n0 + bn) * p.Bn + (k0 + bk));
            Bs[bk][bn] = bv.x; Bs[bk + 1][bn] = bv.y; Bs[bk + 2][bn] = bv.z; Bs[bk + 3][bn] = bv.w;
        }
        __syncthreads();
#pragma unroll
        for (int kk = 0; kk < 16; ++kk) {
            float4 a = *(const float4*)&As[kk][tm];
            float4 b = *(const float4*)&Bs[kk][tn];
            acc[0][0] += a.x * b.x; acc[0][1] += a.x * b.y; acc[0][2] += a.x * b.z; acc[0][3] += a.x * b.w;
            acc[1][0] += a.y * b.x; acc[1][1] += a.y * b.y; acc[1][2] += a.y * b.z; acc[1][3] += a.y * b.w;
            acc[2][0] += a.z * b.x; acc[2][1] += a.z * b.y; acc[2][2] += a.z * b.z; acc[2][3] += a.z * b.w;
            acc[3][0] += a.w * b.x; acc[3][1] += a.w * b.y; acc[3][2] += a.w * b.z; acc[3][3] += a.w * b.w;
        }
        __syncthreads();
    }
#pragma unroll
    for (int i = 0; i < 4; ++i) {
        int m = m0 + tm + i;
        if (m >= p.M) break;
        float* dst = Cb + (long long)(m + p.Crow) * p.Cm + (n0 + tn);
#pragma unroll
        for (int j = 0; j < 4; ++j) {
            float v = p.alpha * acc[i][j];
            if (p.bias) v += p.bias[n0 + tn + j];
            if (p.accum) dst[j] += v; else dst[j] = v;
        }
    }
}

// ---------------- small kernels ----------------
__global__ void cls_set_k(float* H0, const float* cls) {
    int t = blockIdx.x * 256 + threadIdx.x; // 8*512
    int b = t >> 9, c = t & 511;
    H0[(long long)b * NTOK * EMBD + c] = cls[c];
}

// LN of H0 rows into padded LNH (first PADR rows zero)
__global__ __launch_bounds__(256) void ln_pad_k(const float* __restrict__ H0,
                                                float* __restrict__ out,
                                                const float* g, const float* bb) {
    int row = blockIdx.x, b = blockIdx.y, t = threadIdx.x;
    float* o = out + ((long long)b * NP + row) * EMBD;
    if (row < PADR) { o[t] = 0.f; o[t + 256] = 0.f; return; }
    const float* x = H0 + ((long long)b * NTOK + (row - PADR)) * EMBD;
    float v0 = x[t], v1 = x[t + 256];
    float mu = block_sum256(v0 + v1) * (1.f / EMBD);
    float d0 = v0 - mu, d1 = v1 - mu;
    float var = block_sum256(d0 * d0 + d1 * d1) * (1.f / EMBD);
    float rs = 1.f / sqrtf(var + 1e-5f);
    o[t]       = d0 * rs * g[t]       + bb[t];
    o[t + 256] = d1 * rs * g[t + 256] + bb[t + 256];
}

// landmark means of q and k
__global__ void landmark_k(const float* __restrict__ QKV, float* __restrict__ QL,
                           float* __restrict__ KL) {
    long long idx = (long long)blockIdx.x * 256 + threadIdx.x; // 32*256*128
    int d = idx & 127; int i = (int)((idx >> 7) & 255); int bh = (int)(idx >> 15);
    int b = bh >> 2, h = bh & 3;
    const float* base = QKV + (long long)b * NP * 1536 + (long long)i * LSUB * 1536 + h * DHD + d;
    float sq = 0.f, sk = 0.f;
#pragma unroll
    for (int j = 0; j < LSUB; ++j) { sq += base[j * 1536]; sk += base[j * 1536 + EMBD]; }
    QL[idx] = sq * (1.f / LSUB);
    KL[idx] = sk * (1.f / LSUB);
}

__global__ __launch_bounds__(256) void softmax_k(float* __restrict__ X, int L) {
    float* p = X + (long long)blockIdx.x * L;
    int t = threadIdx.x;
    float m = -1e30f;
    for (int i = t; i < L; i += 256) m = fmaxf(m, p[i]);
    m = block_max256(m);
    float s = 0.f;
    for (int i = t; i < L; i += 256) { float e = __expf(p[i] - m); p[i] = e; s += e; }
    s = block_sum256(s);
    float inv = 1.f / s;
    for (int i = t; i < L; i += 256) p[i] *= inv;
}

// pinv init: per-bh row/col abs-sum maxes
__global__ __launch_bounds__(256) void pinv_absmax_k(const float* __restrict__ X, float* red) {
    int bh = blockIdx.x, t = threadIdx.x;
    const float* x = X + (long long)bh * 65536;
    float rs = 0.f, cs = 0.f;
    for (int j = 0; j < 256; ++j) { rs += fabsf(x[t * 256 + j]); cs += fabsf(x[j * 256 + t]); }
    float mr = block_max256(rs);
    float mc = block_max256(cs);
    if (t == 0) { red[bh] = mr; red[32 + bh] = mc; }
}

__global__ void pinv_scalar_k(const float* red, float* inv) {
    float mr = 0.f, mc = 0.f;
    for (int i = 0; i < 32; ++i) { mr = fmaxf(mr, red[i]); mc = fmaxf(mc, red[32 + i]); }
    inv[0] = 1.f / (mr * mc);
}

__global__ void pinv_tinit_k(const float* __restrict__ X, const float* __restrict__ inv,
                             float* __restrict__ Z) {
    long long idx = (long long)blockIdx.x * 256 + threadIdx.x; // 32*65536
    int j = (int)(idx & 255); int i = (int)((idx >> 8) & 255); long long bh = idx >> 16;
    Z[idx] = X[(bh << 16) + ((long long)j << 8) + i] * inv[0];
}

__global__ void eident_k(const float* __restrict__ Min, float* __restrict__ U, float c) {
    long long idx = (long long)blockIdx.x * 256 + threadIdx.x;
    int j = (int)(idx & 255); int i = (int)((idx >> 8) & 255);
    U[idx] = (i == j ? c : 0.f) - Min[idx];
}

// depthwise residual conv on v (kernel 33 along seq), += into ATT2 (rows PADR..NP-1)
__global__ void resconv_k(const float* __restrict__ QKV, const float* __restrict__ rk,
                          float* __restrict__ ATT2) {
    long long idx = (long long)blockIdx.x * 256 + threadIdx.x; // 8*4097*512
    if (idx >= (long long)BATCH * NTOK * EMBD) return;
    int c = (int)(idx & 511); long long r = idx >> 9;
    int n = PADR + (int)(r % NTOK); int b = (int)(r / NTOK);
    int h = c >> 7, d = c & 127;
    const float* vb = QKV + (long long)b * NP * 1536 + 1024 + h * DHD + d;
    float acc = 0.f;
#pragma unroll
    for (int u = 0; u < 33; ++u) {
        int nn = n + u - 16;
        if (nn >= 0 && nn < NP) acc += vb[(long long)nn * 1536] * rk[h * 33 + u];
    }
    ATT2[((long long)b * NP + n) * EMBD + c] += acc;
}

// PPEG: f + dw7 + dw5 + dw3 over the 64x64 token grid
__global__ void ppeg_k(const float* __restrict__ H0,
                       const float* k7, const float* b7,
                       const float* k5, const float* b5,
                       const float* k3, const float* b3,
                       float* __restrict__ TMP) {
    long long idx = (long long)blockIdx.x * 256 + threadIdx.x; // 8*4096*512
    int c = (int)(idx & 511); int pos = (int)((idx >> 9) & 4095); int b = (int)(idx >> 21);
    int y = pos >> 6, x = pos & 63;
    const float* base = H0 + ((long long)b * NTOK + 1) * EMBD + c;
    float acc = base[(long long)pos * EMBD] + b7[c] + b5[c] + b3[c];
#pragma unroll
    for (int dy = 0; dy < 7; ++dy) {
        int yy = y + dy - 3; if ((unsigned)yy >= 64u) continue;
#pragma unroll
        for (int dx = 0; dx < 7; ++dx) {
            int xx = x + dx - 3; if ((unsigned)xx >= 64u) continue;
            acc += base[(long long)(yy * 64 + xx) * EMBD] * k7[c * 49 + dy * 7 + dx];
        }
    }
#pragma unroll
    for (int dy = 0; dy < 5; ++dy) {
        int yy = y + dy - 2; if ((unsigned)yy >= 64u) continue;
#pragma unroll
        for (int dx = 0; dx < 5; ++dx) {
            int xx = x + dx - 2; if ((unsigned)xx >= 64u) continue;
            acc += base[(long long)(yy * 64 + xx) * EMBD] * k5[c * 25 + dy * 5 + dx];
        }
    }
#pragma unroll
    for (int dy = 0; dy < 3; ++dy) {
        int yy = y + dy - 1; if ((unsigned)yy >= 64u) continue;
#pragma unroll
        for (int dx = 0; dx < 3; ++dx) {
            int xx = x + dx - 1; if ((unsigned)xx >= 64u) continue;
            acc += base[(long long)(yy * 64 + xx) * EMBD] * k3[c * 9 + dy * 3 + dx];
        }
    }
    TMP[idx] = acc;
}

__global__ void copyback_k(const float* __restrict__ TMP, float* __restrict__ H0) {
    long long idx = (long long)blockIdx.x * 256 + threadIdx.x; // 8*4096*512
    int c = (int)(idx & 511); int pos = (int)((idx >> 9) & 4095); int b = (int)(idx >> 21);
    H0[((long long)b * NTOK + 1 + pos) * EMBD + c] = TMP[idx];
}

// final LN(row0) . cls_w + cls_b
__global__ __launch_bounds__(256) void head_k(const float* __restrict__ H0, const float* g,
                                              const float* bb, const float* cw, const float* cb,
                                              float* __restrict__ out) {
    int b = blockIdx.x, t = threadIdx.x;
    const float* x = H0 + (long long)b * NTOK * EMBD;
    float v0 = x[t], v1 = x[t + 256];
    float mu = block_sum256(v0 + v1) * (1.f / EMBD);
    float d0 = v0 - mu, d1 = v1 - mu;
    float var = block_sum256(d0 * d0 + d1 * d1) * (1.f / EMBD);
    float rs = 1.f / sqrtf(var + 1e-5f);
    float y0 = d0 * rs * g[t] + bb[t];
    float y1 = d1 * rs * g[t + 256] + bb[t + 256];
    float s = block_sum256(y0 * cw[t] + y1 * cw[t + 256]);
    if (t == 0) out[b] = s + cb[0];
}

// ---------------- host orchestration ----------------
extern "C" void kernel_launch(void* const* d_in, const int* in_sizes, int n_in,
                              void* d_out, int out_size, void* d_ws, size_t ws_size,
                              hipStream_t stream) {
    (void)in_sizes; (void)n_in; (void)out_size; (void)ws_size;
    const float* X        = (const float*)d_in[0];
    const float* few_w    = (const float*)d_in[1];
    const float* few_b    = (const float*)d_in[2];
    const float* cls_tok  = (const float*)d_in[3];
    const float* ln_g[2]  = {(const float*)d_in[4],  (const float*)d_in[10]};
    const float* ln_b[2]  = {(const float*)d_in[5],  (const float*)d_in[11]};
    const float* qkv_w[2] = {(const float*)d_in[6],  (const float*)d_in[12]};
    const float* out_w[2] = {(const float*)d_in[7],  (const float*)d_in[13]};
    const float* out_b[2] = {(const float*)d_in[8],  (const float*)d_in[14]};
    const float* res_k[2] = {(const float*)d_in[9],  (const float*)d_in[15]};
    const float* k7 = (const float*)d_in[16]; const float* b7 = (const float*)d_in[17];
    const float* k5 = (const float*)d_in[18]; const float* b5 = (const float*)d_in[19];
    const float* k3 = (const float*)d_in[20]; const float* b3 = (const float*)d_in[21];
    const float* norm_g = (const float*)d_in[22]; const float* norm_b = (const float*)d_in[23];
    const float* cls_w  = (const float*)d_in[24]; const float* cls_b  = (const float*)d_in[25];
    float* out = (float*)d_out;

    // workspace layout (floats)
    float* ws  = (float*)d_ws;
    float* H0  = ws;                         // 8*4097*512   = 16,781,312
    float* LNH = H0  + 16781312LL;           // 8*4352*512   = 17,825,792  (also ATT2)
    float* QKV = LNH + 17825792LL;           // 8*4352*1536  = 53,477,376  (also PPEG TMP)
    float* A3  = QKV + 53477376LL;           // 32*256*4352  = 35,651,584  (also A1 / pinv temps)
    float* QL  = A3  + 35651584LL;           // 1,048,576
    float* KL  = QL  + 1048576LL;            // 1,048,576
    float* A2  = KL  + 1048576LL;            // 2,097,152
    float* KV  = A2  + 2097152LL;            // 1,048,576
    float* ZKV = KV  + 1048576LL;            // 1,048,576
    float* RED = ZKV + 1048576LL;            // 65 floats (maxes + inv scalar)
    float* Zb0 = A3;                 // pinv temps overlay A3 (dead after KV gemm)
    float* Zb1 = A3 + 2097152LL;
    float* XZm = A3 + 4194304LL;
    float* U1  = A3 + 6291456LL;
    float* U2  = A3 + 8388608LL;

    auto gemm = [&](const float* A, long long As1, long long As2, int Adiv, int Am, int Arow,
                    const float* Bm, long long Bs1, long long Bs2, int Bdiv, int Bk, int Bn,
                    float* C, long long Cs1, long long Cs2, int Cdiv, int Cm, int Crow,
                    int M, int N, int K, int nb, float alpha, int accum, const float* bias) {
        GemmP p;
        p.A = A; p.B = Bm; p.C = C; p.bias = bias;
        p.As1 = As1; p.As2 = As2; p.Bs1 = Bs1; p.Bs2 = Bs2; p.Cs1 = Cs1; p.Cs2 = Cs2;
        p.Adiv = Adiv; p.Bdiv = Bdiv; p.Cdiv = Cdiv;
        p.Am = Am; p.Bk = Bk; p.Bn = Bn; p.Cm = Cm; p.Arow = Arow; p.Crow = Crow;
        p.M = M; p.N = N; p.K = K; p.nb = nb; p.alpha = alpha; p.accum = accum;
        dim3 grid(N / 64, (M + 63) / 64, nb);
        gemm_k<<<grid, 256, 0, stream>>>(p);
    };

    // ---- stem: cls token + few-shot linear ----
    cls_set_k<<<16, 256, 0, stream>>>(H0, cls_tok);
    gemm(X, 4194304LL, 0, 1, 1024, 0,
         few_w, 0, 0, 1, 512, 1,
         H0, 2097664LL, 0, 1, 512, 1,
         4096, 512, 1024, BATCH, 1.f, 0, few_b);

    for (int L = 0; L < 2; ++L) {
        // LN + zero-pad
        ln_pad_k<<<dim3(NP, BATCH), 256, 0, stream>>>(H0, LNH, ln_g[L], ln_b[L]);
        // qkv
        gemm(LNH, 0, 0, 1, 512, 0,
             qkv_w[L], 0, 0, 1, 1536, 1,
             QKV, 0, 0, 1, 1536, 0,
             BATCH * NP, 1536, 512, 1, 1.f, 0, nullptr);
        // landmarks
        landmark_k<<<4096, 256, 0, stream>>>(QKV, QL, KL);
        // a2 = softmax(SCALE * QL @ KL^T)
        gemm(QL, 32768LL, 0, 1, 128, 0,
             KL, 32768LL, 0, 1, 1, 128,
             A2, 65536LL, 0, 1, 256, 0,
             256, 256, 128, 32, SCALE_F, 0, nullptr);
        softmax_k<<<32 * 256, 256, 0, stream>>>(A2, 256);
        // a3 = softmax(SCALE * QL @ K^T)
        gemm(QL, 32768LL, 0, 1, 128, 0,
             QKV + 512, 6680064LL, 128LL, 4, 1, 1536,
             A3, 1114112LL, 0, 1, 4352, 0,
             256, 4352, 128, 32, SCALE_F, 0, nullptr);
        softmax_k<<<32 * 256, 256, 0, stream>>>(A3, 4352);
        // KV = a3 @ V
        gemm(A3, 1114112LL, 0, 1, 4352, 0,
             QKV + 1024, 6680064LL, 128LL, 4, 1536, 1,
             KV, 32768LL, 0, 1, 128, 0,
             256, 128, 4352, 32, 1.f, 0, nullptr);
        // pinv(a2): global-scalar init, then 6 Newton iterations
        pinv_absmax_k<<<32, 256, 0, stream>>>(A2, RED);
        pinv_scalar_k<<<1, 1, 0, stream>>>(RED, RED + 64);
        pinv_tinit_k<<<8192, 256, 0, stream>>>(A2, RED + 64, Zb0);
        float* zc = Zb0; float* zn = Zb1;
        for (int it = 0; it < 6; ++it) {
            gemm(A2, 65536LL, 0, 1, 256, 0, zc, 65536LL, 0, 1, 256, 1,
                 XZm, 65536LL, 0, 1, 256, 0, 256, 256, 256, 32, 1.f, 0, nullptr);
            eident_k<<<8192, 256, 0, stream>>>(XZm, U1, 7.f);
            gemm(XZm, 65536LL, 0, 1, 256, 0, U1, 65536LL, 0, 1, 256, 1,
                 U2, 65536LL, 0, 1, 256, 0, 256, 256, 256, 32, 1.f, 0, nullptr);
            eident_k<<<8192, 256, 0, stream>>>(U2, U1, 15.f);
            gemm(XZm, 65536LL, 0, 1, 256, 0, U1, 65536LL, 0, 1, 256, 1,
                 U2, 65536LL, 0, 1, 256, 0, 256, 256, 256, 32, 1.f, 0, nullptr);
            eident_k<<<8192, 256, 0, stream>>>(U2, U1, 13.f);
            gemm(zc, 65536LL, 0, 1, 256, 0, U1, 65536LL, 0, 1, 256, 1,
                 zn, 65536LL, 0, 1, 256, 0, 256, 256, 256, 32, 0.25f, 0, nullptr);
            float* t2 = zc; zc = zn; zn = t2;
        }
        // ZKV = pinv @ KV
        gemm(zc, 65536LL, 0, 1, 256, 0,
             KV, 32768LL, 0, 1, 128, 1,
             ZKV, 32768LL, 0, 1, 128, 0,
             256, 128, 256, 32, 1.f, 0, nullptr);
        // a1 = softmax(SCALE * Q @ KL^T)   (overwrites A3 region)
        gemm(QKV, 6680064LL, 128LL, 4, 1536, 0,
             KL, 32768LL, 0, 1, 1, 128,
             A3, 1114112LL, 0, 1, 256, 0,
             4352, 256, 128, 32, SCALE_F, 0, nullptr);
        softmax_k<<<32 * 4352, 256, 0, stream>>>(A3, 256);
        // ATT2 = a1 @ ZKV  (head-interleaved channel layout, into LNH region)
        gemm(A3, 1114112LL, 0, 1, 256, 0,
             ZKV, 32768LL, 0, 1, 128, 1,
             LNH, 2228224LL, 128LL, 4, 512, 0,
             4352, 128, 256, 32, 1.f, 0, nullptr);
        // += depthwise residual conv of V
        resconv_k<<<65552, 256, 0, stream>>>(QKV, res_k[L], LNH);
        // H0 += ATT2[PADR:] @ out_w + out_b
        gemm(LNH, 2228224LL, 0, 1, 512, PADR,
             out_w[L], 0, 0, 1, 512, 1,
             H0, 2097664LL, 0, 1, 512, 0,
             NTOK, 512, 512, BATCH, 1.f, 1, out_b[L]);

        if (L == 0) {
            ppeg_k<<<65536, 256, 0, stream>>>(H0, k7, b7, k5, b5, k3, b3, QKV);
            copyback_k<<<65536, 256, 0, stream>>>(QKV, H0);
        }
    }

    head_k<<<BATCH, 256, 0, stream>>>(H0, norm_g, norm_b, cls_w, cls_b, out);
}

// Round 2
// 7326.905 us; speedup vs baseline: 1.4278x; 1.4278x over previous
//
#include <hip/hip_runtime.h>

// ---------------- constants ----------------
constexpr int BATCH = 8;
constexpr int NTOK  = 4097;   // 1 cls + 4096 tokens
constexpr int NP    = 4352;   // padded seq len (multiple of 256)
constexpr int PADR  = 255;    // zero rows prepended
constexpr int EMBD  = 512;
constexpr int DHD   = 128;
constexpr int LSUB  = 17;     // NP / 256 landmarks
constexpr float SCALE_F = 0.08838834764831845f; // 128^-0.5

// ---------------- block reductions (blockDim == 256) ----------------
__device__ __forceinline__ float block_sum256(float v) {
    __shared__ float tmp[4];
    __syncthreads();
#pragma unroll
    for (int off = 32; off > 0; off >>= 1) v += __shfl_down(v, off, 64);
    int t = threadIdx.x;
    if ((t & 63) == 0) tmp[t >> 6] = v;
    __syncthreads();
    return tmp[0] + tmp[1] + tmp[2] + tmp[3];
}

__device__ __forceinline__ float block_max256(float v) {
    __shared__ float tmp[4];
    __syncthreads();
#pragma unroll
    for (int off = 32; off > 0; off >>= 1) v = fmaxf(v, __shfl_down(v, off, 64));
    int t = threadIdx.x;
    if ((t & 63) == 0) tmp[t >> 6] = v;
    __syncthreads();
    return fmaxf(fmaxf(tmp[0], tmp[1]), fmaxf(tmp[2], tmp[3]));
}

// ---------------- generic batched fp32 GEMM ----------------
// C = cdiagc*I - [ alpha * A @ B' (+bias) ]   (transforms optional)
// B' = bdiagc*I - B  when btrans (only in Bn==1 path)
// A addr: Abase(bz) + (m+Arow)*Am + k          (k-stride 1)
// B addr: Bbase(bz) + k*Bk + n*Bn              (Bn==1 or Bk==1)
// C addr: Cbase(bz) + (m+Crow)*Cm + n
struct GemmP {
    const float* A; const float* B; float* C; const float* bias;
    long long As1, As2, Bs1, Bs2, Cs1, Cs2;
    int Adiv, Bdiv, Cdiv;
    int Am, Bk, Bn, Cm, Arow, Crow;
    int M, N, K, nb;
    float alpha; int accum;
    float bdiagc; int btrans; float cdiagc; int ctrans;
};

__global__ __launch_bounds__(256) void gemm_k(GemmP p) {
    __shared__ float As[16][64];
    __shared__ float Bs[16][64];
    const int bz = blockIdx.z;
    const float* Ab = p.A + (long long)(bz / p.Adiv) * p.As1 + (long long)(bz % p.Adiv) * p.As2;
    const float* Bb = p.B + (long long)(bz / p.Bdiv) * p.Bs1 + (long long)(bz % p.Bdiv) * p.Bs2;
    float*       Cb = p.C + (long long)(bz / p.Cdiv) * p.Cs1 + (long long)(bz % p.Cdiv) * p.Cs2;
    const int m0 = blockIdx.y * 64, n0 = blockIdx.x * 64;
    const int t = threadIdx.x;
    const int tm = (t >> 4) << 2, tn = (t & 15) << 2;
    const int ar = t >> 2, ak = (t & 3) << 2;
    float acc[4][4] = {{0.f}};
    float4 av, bv;

    auto loadTiles = [&](int k0) {
        av = make_float4(0.f, 0.f, 0.f, 0.f);
        if (m0 + ar < p.M)
            av = *(const float4*)(Ab + (long long)(m0 + ar + p.Arow) * p.Am + (k0 + ak));
        if (p.Bn == 1) {
            const int bk = t >> 4, bn = (t & 15) << 2;
            bv = *(const float4*)(Bb + (long long)(k0 + bk) * p.Bk + (n0 + bn));
            if (p.btrans) {
                const int gk = k0 + bk, gn = n0 + bn;
                bv.x = (gk == gn     ? p.bdiagc : 0.f) - bv.x;
                bv.y = (gk == gn + 1 ? p.bdiagc : 0.f) - bv.y;
                bv.z = (gk == gn + 2 ? p.bdiagc : 0.f) - bv.z;
                bv.w = (gk == gn + 3 ? p.bdiagc : 0.f) - bv.w;
            }
        } else {
            const int bn = t >> 2, bk = (t & 3) << 2;
            bv = *(const float4*)(Bb + (long long)(n0 + bn) * p.Bn + (k0 + bk));
        }
    };
    auto storeTiles = [&]() {
        As[ak][ar] = av.x; As[ak + 1][ar] = av.y; As[ak + 2][ar] = av.z; As[ak + 3][ar] = av.w;
        if (p.Bn == 1) {
            const int bk = t >> 4, bn = (t & 15) << 2;
            *(float4*)&Bs[bk][bn] = bv;
        } else {
            const int bn = t >> 2, bk = (t & 3) << 2;
            Bs[bk][bn] = bv.x; Bs[bk + 1][bn] = bv.y; Bs[bk + 2][bn] = bv.z; Bs[bk + 3][bn] = bv.w;
        }
    };

    loadTiles(0);
    for (int k0 = 0; k0 < p.K; k0 += 16) {
        storeTiles();
        __syncthreads();
        if (k0 + 16 < p.K) loadTiles(k0 + 16);   // prefetch overlaps compute
#pragma unroll
        for (int kk = 0; kk < 16; ++kk) {
            float4 a = *(const float4*)&As[kk][tm];
            float4 b = *(const float4*)&Bs[kk][tn];
            acc[0][0] += a.x * b.x; acc[0][1] += a.x * b.y; acc[0][2] += a.x * b.z; acc[0][3] += a.x * b.w;
            acc[1][0] += a.y * b.x; acc[1][1] += a.y * b.y; acc[1][2] += a.y * b.z; acc[1][3] += a.y * b.w;
            acc[2][0] += a.z * b.x; acc[2][1] += a.z * b.y; acc[2][2] += a.z * b.z; acc[2][3] += a.z * b.w;
            acc[3][0] += a.w * b.x; acc[3][1] += a.w * b.y; acc[3][2] += a.w * b.z; acc[3][3] += a.w * b.w;
        }
        __syncthreads();
    }
#pragma unroll
    for (int i = 0; i < 4; ++i) {
        int m = m0 + tm + i;
        if (m >= p.M) break;
        float* dst = Cb + (long long)(m + p.Crow) * p.Cm + (n0 + tn);
#pragma unroll
        for (int j = 0; j < 4; ++j) {
            float v = p.alpha * acc[i][j];
            if (p.bias) v += p.bias[n0 + tn + j];
            if (p.ctrans) v = (m == n0 + tn + j ? p.cdiagc : 0.f) - v;
            if (p.accum) dst[j] += v; else dst[j] = v;
        }
    }
}

// ---------------- small kernels ----------------
__global__ void cls_set_k(float* H0, const float* cls) {
    int t = blockIdx.x * 256 + threadIdx.x; // 8*512
    int b = t >> 9, c = t & 511;
    H0[(long long)b * NTOK * EMBD + c] = cls[c];
}

__global__ __launch_bounds__(256) void ln_pad_k(const float* __restrict__ H0,
                                                float* __restrict__ out,
                                                const float* g, const float* bb) {
    int row = blockIdx.x, b = blockIdx.y, t = threadIdx.x;
    float* o = out + ((long long)b * NP + row) * EMBD;
    if (row < PADR) { o[t] = 0.f; o[t + 256] = 0.f; return; }
    const float* x = H0 + ((long long)b * NTOK + (row - PADR)) * EMBD;
    float v0 = x[t], v1 = x[t + 256];
    float mu = block_sum256(v0 + v1) * (1.f / EMBD);
    float d0 = v0 - mu, d1 = v1 - mu;
    float var = block_sum256(d0 * d0 + d1 * d1) * (1.f / EMBD);
    float rs = 1.f / sqrtf(var + 1e-5f);
    o[t]       = d0 * rs * g[t]       + bb[t];
    o[t + 256] = d1 * rs * g[t + 256] + bb[t + 256];
}

__global__ void landmark_k(const float* __restrict__ QKV, float* __restrict__ QL,
                           float* __restrict__ KL) {
    long long idx = (long long)blockIdx.x * 256 + threadIdx.x; // 32*256*128
    int d = idx & 127; int i = (int)((idx >> 7) & 255); int bh = (int)(idx >> 15);
    int b = bh >> 2, h = bh & 3;
    const float* base = QKV + (long long)b * NP * 1536 + (long long)i * LSUB * 1536 + h * DHD + d;
    float sq = 0.f, sk = 0.f;
#pragma unroll
    for (int j = 0; j < LSUB; ++j) { sq += base[j * 1536]; sk += base[j * 1536 + EMBD]; }
    QL[idx] = sq * (1.f / LSUB);
    KL[idx] = sk * (1.f / LSUB);
}

// wave-per-row softmax for rows of exactly 256 floats
__global__ __launch_bounds__(256) void softmax256_k(float* __restrict__ X) {
    long long row = (long long)blockIdx.x * 4 + (threadIdx.x >> 6);
    int lane = threadIdx.x & 63;
    float4* p = (float4*)(X + row * 256) + lane;
    float4 v = *p;
    float m = fmaxf(fmaxf(v.x, v.y), fmaxf(v.z, v.w));
#pragma unroll
    for (int off = 32; off > 0; off >>= 1) m = fmaxf(m, __shfl_xor(m, off, 64));
    float ex = __expf(v.x - m), ey = __expf(v.y - m), ez = __expf(v.z - m), ew = __expf(v.w - m);
    float s = ex + ey + ez + ew;
#pragma unroll
    for (int off = 32; off > 0; off >>= 1) s += __shfl_xor(s, off, 64);
    float inv = 1.f / s;
    *p = make_float4(ex * inv, ey * inv, ez * inv, ew * inv);
}

// block-per-row softmax, float4 vectorized (L % 1024 == 0 path not required; L%4==0)
__global__ __launch_bounds__(256) void softmax_k(float* __restrict__ X, int L) {
    float4* p = (float4*)(X + (long long)blockIdx.x * L);
    int nv = L >> 2, t = threadIdx.x;
    float m = -1e30f;
    for (int i = t; i < nv; i += 256) {
        float4 v = p[i];
        m = fmaxf(m, fmaxf(fmaxf(v.x, v.y), fmaxf(v.z, v.w)));
    }
    m = block_max256(m);
    float s = 0.f;
    for (int i = t; i < nv; i += 256) {
        float4 v = p[i];
        v.x = __expf(v.x - m); v.y = __expf(v.y - m); v.z = __expf(v.z - m); v.w = __expf(v.w - m);
        p[i] = v;
        s += v.x + v.y + v.z + v.w;
    }
    s = block_sum256(s);
    float inv = 1.f / s;
    for (int i = t; i < nv; i += 256) {
        float4 v = p[i];
        p[i] = make_float4(v.x * inv, v.y * inv, v.z * inv, v.w * inv);
    }
}

__global__ __launch_bounds__(256) void pinv_absmax_k(const float* __restrict__ X, float* red) {
    int bh = blockIdx.x, t = threadIdx.x;
    const float* x = X + (long long)bh * 65536;
    float rs = 0.f, cs = 0.f;
    for (int j = 0; j < 256; ++j) { rs += fabsf(x[t * 256 + j]); cs += fabsf(x[j * 256 + t]); }
    float mr = block_max256(rs);
    float mc = block_max256(cs);
    if (t == 0) { red[bh] = mr; red[32 + bh] = mc; }
}

__global__ void pinv_scalar_k(const float* red, float* inv) {
    float mr = 0.f, mc = 0.f;
    for (int i = 0; i < 32; ++i) { mr = fmaxf(mr, red[i]); mc = fmaxf(mc, red[32 + i]); }
    inv[0] = 1.f / (mr * mc);
}

__global__ void pinv_tinit_k(const float* __restrict__ X, const float* __restrict__ inv,
                             float* __restrict__ Z) {
    long long idx = (long long)blockIdx.x * 256 + threadIdx.x; // 32*65536
    int j = (int)(idx & 255); int i = (int)((idx >> 8) & 255); long long bh = idx >> 16;
    Z[idx] = X[(bh << 16) + ((long long)j << 8) + i] * inv[0];
}

// depthwise residual conv on v (kernel 33 along seq), += into ATT2 (rows PADR..NP-1)
__global__ void resconv_k(const float* __restrict__ QKV, const float* __restrict__ rk,
                          float* __restrict__ ATT2) {
    long long idx = (long long)blockIdx.x * 256 + threadIdx.x; // 8*4097*512
    if (idx >= (long long)BATCH * NTOK * EMBD) return;
    int c = (int)(idx & 511); long long r = idx >> 9;
    int n = PADR + (int)(r % NTOK); int b = (int)(r / NTOK);
    int h = c >> 7, d = c & 127;
    const float* vb = QKV + (long long)b * NP * 1536 + 1024 + h * DHD + d;
    float acc = 0.f;
#pragma unroll
    for (int u = 0; u < 33; ++u) {
        int nn = n + u - 16;
        if (nn >= 0 && nn < NP) acc += vb[(long long)nn * 1536] * rk[h * 33 + u];
    }
    ATT2[((long long)b * NP + n) * EMBD + c] += acc;
}

// PPEG v2: fixed channel per thread, weights in registers, loop over positions.
// grid: (32 pos-tiles of 128, 2 channel groups, 8 batch)
__global__ __launch_bounds__(256) void ppeg2_k(const float* __restrict__ H0,
                                               const float* __restrict__ k7, const float* __restrict__ b7,
                                               const float* __restrict__ k5, const float* __restrict__ b5,
                                               const float* __restrict__ k3, const float* __restrict__ b3,
                                               float* __restrict__ TMP) {
    const int c = blockIdx.y * 256 + threadIdx.x;
    const int b = blockIdx.z;
    const float* base = H0 + ((long long)b * NTOK + 1) * EMBD + c;
    float w7[49], w5[25], w3[9];
#pragma unroll
    for (int i = 0; i < 49; ++i) w7[i] = k7[c * 49 + i];
#pragma unroll
    for (int i = 0; i < 25; ++i) w5[i] = k5[c * 25 + i];
#pragma unroll
    for (int i = 0; i < 9; ++i)  w3[i] = k3[c * 9 + i];
    const float bias = b7[c] + b5[c] + b3[c];
    float* tb = TMP + ((long long)b * 4096) * EMBD + c;

    const int p0 = blockIdx.x * 128;
    for (int pp = 0; pp < 128; ++pp) {
        const int pos = p0 + pp;          // uniform across block
        const int y = pos >> 6, x = pos & 63;
        float acc = base[(long long)pos * EMBD] + bias;
        if (y >= 3 && y < 61 && x >= 3 && x < 61) {  // interior fast path (uniform branch)
#pragma unroll
            for (int dy = 0; dy < 7; ++dy)
#pragma unroll
                for (int dx = 0; dx < 7; ++dx)
                    acc += base[(long long)(pos + (dy - 3) * 64 + (dx - 3)) * EMBD] * w7[dy * 7 + dx];
#pragma unroll
            for (int dy = 0; dy < 5; ++dy)
#pragma unroll
                for (int dx = 0; dx < 5; ++dx)
                    acc += base[(long long)(pos + (dy - 2) * 64 + (dx - 2)) * EMBD] * w5[dy * 5 + dx];
#pragma unroll
            for (int dy = 0; dy < 3; ++dy)
#pragma unroll
                for (int dx = 0; dx < 3; ++dx)
                    acc += base[(long long)(pos + (dy - 1) * 64 + (dx - 1)) * EMBD] * w3[dy * 3 + dx];
        } else {
#pragma unroll
            for (int dy = 0; dy < 7; ++dy) {
                int yy = y + dy - 3; if ((unsigned)yy >= 64u) continue;
#pragma unroll
                for (int dx = 0; dx < 7; ++dx) {
                    int xx = x + dx - 3; if ((unsigned)xx >= 64u) continue;
                    acc += base[(long long)(yy * 64 + xx) * EMBD] * w7[dy * 7 + dx];
                }
            }
#pragma unroll
            for (int dy = 0; dy < 5; ++dy) {
                int yy = y + dy - 2; if ((unsigned)yy >= 64u) continue;
#pragma unroll
                for (int dx = 0; dx < 5; ++dx) {
                    int xx = x + dx - 2; if ((unsigned)xx >= 64u) continue;
                    acc += base[(long long)(yy * 64 + xx) * EMBD] * w5[dy * 5 + dx];
                }
            }
#pragma unroll
            for (int dy = 0; dy < 3; ++dy) {
                int yy = y + dy - 1; if ((unsigned)yy >= 64u) continue;
#pragma unroll
                for (int dx = 0; dx < 3; ++dx) {
                    int xx = x + dx - 1; if ((unsigned)xx >= 64u) continue;
                    acc += base[(long long)(yy * 64 + xx) * EMBD] * w3[dy * 3 + dx];
                }
            }
        }
        tb[(long long)pos * EMBD] = acc;
    }
}

__global__ void copyback_k(const float* __restrict__ TMP, float* __restrict__ H0) {
    long long idx = (long long)blockIdx.x * 256 + threadIdx.x; // 8*4096*512
    int c = (int)(idx & 511); int pos = (int)((idx >> 9) & 4095); int b = (int)(idx >> 21);
    H0[((long long)b * NTOK + 1 + pos) * EMBD + c] = TMP[idx];
}

__global__ __launch_bounds__(256) void head_k(const float* __restrict__ H0, const float* g,
                                              const float* bb, const float* cw, const float* cb,
                                              float* __restrict__ out) {
    int b = blockIdx.x, t = threadIdx.x;
    const float* x = H0 + (long long)b * NTOK * EMBD;
    float v0 = x[t], v1 = x[t + 256];
    float mu = block_sum256(v0 + v1) * (1.f / EMBD);
    float d0 = v0 - mu, d1 = v1 - mu;
    float var = block_sum256(d0 * d0 + d1 * d1) * (1.f / EMBD);
    float rs = 1.f / sqrtf(var + 1e-5f);
    float y0 = d0 * rs * g[t] + bb[t];
    float y1 = d1 * rs * g[t + 256] + bb[t + 256];
    float s = block_sum256(y0 * cw[t] + y1 * cw[t + 256]);
    if (t == 0) out[b] = s + cb[0];
}

// ---------------- host orchestration ----------------
extern "C" void kernel_launch(void* const* d_in, const int* in_sizes, int n_in,
                              void* d_out, int out_size, void* d_ws, size_t ws_size,
                              hipStream_t stream) {
    (void)in_sizes; (void)n_in; (void)out_size; (void)ws_size;
    const float* X        = (const float*)d_in[0];
    const float* few_w    = (const float*)d_in[1];
    const float* few_b    = (const float*)d_in[2];
    const float* cls_tok  = (const float*)d_in[3];
    const float* ln_g[2]  = {(const float*)d_in[4],  (const float*)d_in[10]};
    const float* ln_b[2]  = {(const float*)d_in[5],  (const float*)d_in[11]};
    const float* qkv_w[2] = {(const float*)d_in[6],  (const float*)d_in[12]};
    const float* out_w[2] = {(const float*)d_in[7],  (const float*)d_in[13]};
    const float* out_b[2] = {(const float*)d_in[8],  (const float*)d_in[14]};
    const float* res_k[2] = {(const float*)d_in[9],  (const float*)d_in[15]};
    const float* k7 = (const float*)d_in[16]; const float* b7 = (const float*)d_in[17];
    const float* k5 = (const float*)d_in[18]; const float* b5 = (const float*)d_in[19];
    const float* k3 = (const float*)d_in[20]; const float* b3 = (const float*)d_in[21];
    const float* norm_g = (const float*)d_in[22]; const float* norm_b = (const float*)d_in[23];
    const float* cls_w  = (const float*)d_in[24]; const float* cls_b  = (const float*)d_in[25];
    float* out = (float*)d_out;

    // workspace layout (floats)
    float* ws  = (float*)d_ws;
    float* H0  = ws;                         // 8*4097*512
    float* LNH = H0  + 16781312LL;           // 8*4352*512   (also ATT2)
    float* QKV = LNH + 17825792LL;           // 8*4352*1536  (also PPEG TMP)
    float* A3  = QKV + 53477376LL;           // 32*256*4352  (also A1 / pinv temps)
    float* QL  = A3  + 35651584LL;
    float* KL  = QL  + 1048576LL;
    float* A2  = KL  + 1048576LL;
    float* KV  = A2  + 2097152LL;
    float* ZKV = KV  + 1048576LL;
    float* RED = ZKV + 1048576LL;
    float* Zb0 = A3;                 // pinv temps overlay A3 (dead after KV gemm)
    float* Zb1 = A3 + 2097152LL;
    float* XZm = A3 + 4194304LL;

    auto gemmx = [&](const float* A, long long As1, long long As2, int Adiv, int Am, int Arow,
                     const float* Bm, long long Bs1, long long Bs2, int Bdiv, int Bk, int Bn,
                     float* C, long long Cs1, long long Cs2, int Cdiv, int Cm, int Crow,
                     int M, int N, int K, int nb, float alpha, int accum, const float* bias,
                     float bdiagc, int btrans, float cdiagc, int ctrans) {
        GemmP p;
        p.A = A; p.B = Bm; p.C = C; p.bias = bias;
        p.As1 = As1; p.As2 = As2; p.Bs1 = Bs1; p.Bs2 = Bs2; p.Cs1 = Cs1; p.Cs2 = Cs2;
        p.Adiv = Adiv; p.Bdiv = Bdiv; p.Cdiv = Cdiv;
        p.Am = Am; p.Bk = Bk; p.Bn = Bn; p.Cm = Cm; p.Arow = Arow; p.Crow = Crow;
        p.M = M; p.N = N; p.K = K; p.nb = nb; p.alpha = alpha; p.accum = accum;
        p.bdiagc = bdiagc; p.btrans = btrans; p.cdiagc = cdiagc; p.ctrans = ctrans;
        dim3 grid(N / 64, (M + 63) / 64, nb);
        gemm_k<<<grid, 256, 0, stream>>>(p);
    };
    auto gemm = [&](const float* A, long long As1, long long As2, int Adiv, int Am, int Arow,
                    const float* Bm, long long Bs1, long long Bs2, int Bdiv, int Bk, int Bn,
                    float* C, long long Cs1, long long Cs2, int Cdiv, int Cm, int Crow,
                    int M, int N, int K, int nb, float alpha, int accum, const float* bias) {
        gemmx(A, As1, As2, Adiv, Am, Arow, Bm, Bs1, Bs2, Bdiv, Bk, Bn,
              C, Cs1, Cs2, Cdiv, Cm, Crow, M, N, K, nb, alpha, accum, bias, 0.f, 0, 0.f, 0);
    };

    // ---- stem: cls token + few-shot linear ----
    cls_set_k<<<16, 256, 0, stream>>>(H0, cls_tok);
    gemm(X, 4194304LL, 0, 1, 1024, 0,
         few_w, 0, 0, 1, 512, 1,
         H0, 2097664LL, 0, 1, 512, 1,
         4096, 512, 1024, BATCH, 1.f, 0, few_b);

    for (int L = 0; L < 2; ++L) {
        ln_pad_k<<<dim3(NP, BATCH), 256, 0, stream>>>(H0, LNH, ln_g[L], ln_b[L]);
        gemm(LNH, 0, 0, 1, 512, 0,
             qkv_w[L], 0, 0, 1, 1536, 1,
             QKV, 0, 0, 1, 1536, 0,
             BATCH * NP, 1536, 512, 1, 1.f, 0, nullptr);
        landmark_k<<<4096, 256, 0, stream>>>(QKV, QL, KL);
        // a2 = softmax(SCALE * QL @ KL^T)
        gemm(QL, 32768LL, 0, 1, 128, 0,
             KL, 32768LL, 0, 1, 1, 128,
             A2, 65536LL, 0, 1, 256, 0,
             256, 256, 128, 32, SCALE_F, 0, nullptr);
        softmax256_k<<<2048, 256, 0, stream>>>(A2);
        // a3 = softmax(SCALE * QL @ K^T)
        gemm(QL, 32768LL, 0, 1, 128, 0,
             QKV + 512, 6680064LL, 128LL, 4, 1, 1536,
             A3, 1114112LL, 0, 1, 4352, 0,
             256, 4352, 128, 32, SCALE_F, 0, nullptr);
        softmax_k<<<8192, 256, 0, stream>>>(A3, 4352);
        // KV = a3 @ V
        gemm(A3, 1114112LL, 0, 1, 4352, 0,
             QKV + 1024, 6680064LL, 128LL, 4, 1536, 1,
             KV, 32768LL, 0, 1, 128, 0,
             256, 128, 4352, 32, 1.f, 0, nullptr);
        // pinv(a2): global-scalar init, then 6 Newton iterations (4 fused gemms each)
        pinv_absmax_k<<<32, 256, 0, stream>>>(A2, RED);
        pinv_scalar_k<<<1, 1, 0, stream>>>(RED, RED + 64);
        pinv_tinit_k<<<8192, 256, 0, stream>>>(A2, RED + 64, Zb0);
        float* zc = Zb0; float* zn = Zb1;
        for (int it = 0; it < 6; ++it) {
            float* U1 = A3 + 6291456LL;  // scratch
            // P = A2 @ zc
            gemm(A2, 65536LL, 0, 1, 256, 0, zc, 65536LL, 0, 1, 256, 1,
                 XZm, 65536LL, 0, 1, 256, 0, 256, 256, 256, 32, 1.f, 0, nullptr);
            // U1 = 15I - P @ (7I - P)
            gemmx(XZm, 65536LL, 0, 1, 256, 0, XZm, 65536LL, 0, 1, 256, 1,
                  U1, 65536LL, 0, 1, 256, 0, 256, 256, 256, 32, 1.f, 0, nullptr,
                  7.f, 1, 15.f, 1);
            // zn(tmp) = 13I - P @ U1  -> store into scratch U2
            float* U2 = A3 + 8388608LL;
            gemmx(XZm, 65536LL, 0, 1, 256, 0, U1, 65536LL, 0, 1, 256, 1,
                  U2, 65536LL, 0, 1, 256, 0, 256, 256, 256, 32, 1.f, 0, nullptr,
                  0.f, 0, 13.f, 1);
            // zn = 0.25 * zc @ U2
            gemm(zc, 65536LL, 0, 1, 256, 0, U2, 65536LL, 0, 1, 256, 1,
                 zn, 65536LL, 0, 1, 256, 0, 256, 256, 256, 32, 0.25f, 0, nullptr);
            float* t2 = zc; zc = zn; zn = t2;
        }
        // ZKV = pinv @ KV
        gemm(zc, 65536LL, 0, 1, 256, 0,
             KV, 32768LL, 0, 1, 128, 1,
             ZKV, 32768LL, 0, 1, 128, 0,
             256, 128, 256, 32, 1.f, 0, nullptr);
        // a1 = softmax(SCALE * Q @ KL^T)
        gemm(QKV, 6680064LL, 128LL, 4, 1536, 0,
             KL, 32768LL, 0, 1, 1, 128,
             A3, 1114112LL, 0, 1, 256, 0,
             4352, 256, 128, 32, SCALE_F, 0, nullptr);
        softmax256_k<<<34816, 256, 0, stream>>>(A3);
        // ATT2 = a1 @ ZKV
        gemm(A3, 1114112LL, 0, 1, 256, 0,
             ZKV, 32768LL, 0, 1, 128, 1,
             LNH, 2228224LL, 128LL, 4, 512, 0,
             4352, 128, 256, 32, 1.f, 0, nullptr);
        resconv_k<<<65552, 256, 0, stream>>>(QKV, res_k[L], LNH);
        // H0 += ATT2[PADR:] @ out_w + out_b
        gemm(LNH, 2228224LL, 0, 1, 512, PADR,
             out_w[L], 0, 0, 1, 512, 1,
             H0, 2097664LL, 0, 1, 512, 0,
             NTOK, 512, 512, BATCH, 1.f, 1, out_b[L]);

        if (L == 0) {
            ppeg2_k<<<dim3(32, 2, 8), 256, 0, stream>>>(H0, k7, b7, k5, b5, k3, b3, QKV);
            copyback_k<<<65536, 256, 0, stream>>>(QKV, H0);
        }
    }

    head_k<<<BATCH, 256, 0, stream>>>(H0, norm_g, norm_b, cls_w, cls_b, out);
}

// Round 3
// 5893.916 us; speedup vs baseline: 1.7749x; 1.2431x over previous
//
#include <hip/hip_runtime.h>

// ---------------- constants ----------------
constexpr int BATCH = 8;
constexpr int NTOK  = 4097;   // 1 cls + 4096 tokens
constexpr int NP    = 4352;   // padded seq len (multiple of 256)
constexpr int PADR  = 255;    // zero rows prepended
constexpr int EMBD  = 512;
constexpr int DHD   = 128;
constexpr int LSUB  = 17;     // NP / 256 landmarks
constexpr float SCALE_F = 0.08838834764831845f; // 128^-0.5

typedef unsigned short u16;
typedef short   s16x8 __attribute__((ext_vector_type(8)));
typedef u16     u16x4 __attribute__((ext_vector_type(4)));
typedef float   f32x4 __attribute__((ext_vector_type(4)));

__device__ __forceinline__ u16 f2bf(float x) {   // fp32 -> bf16 bits, RNE
    unsigned u = __float_as_uint(x);
    u += 0x7fffu + ((u >> 16) & 1u);
    return (u16)(u >> 16);
}
__device__ __forceinline__ float bf2f(u16 h) {
    return __uint_as_float(((unsigned)h) << 16);
}

// ---------------- block reductions (blockDim == 256) ----------------
__device__ __forceinline__ float block_sum256(float v) {
    __shared__ float tmp[4];
    __syncthreads();
#pragma unroll
    for (int off = 32; off > 0; off >>= 1) v += __shfl_down(v, off, 64);
    int t = threadIdx.x;
    if ((t & 63) == 0) tmp[t >> 6] = v;
    __syncthreads();
    return tmp[0] + tmp[1] + tmp[2] + tmp[3];
}

__device__ __forceinline__ float block_max256(float v) {
    __shared__ float tmp[4];
    __syncthreads();
#pragma unroll
    for (int off = 32; off > 0; off >>= 1) v = fmaxf(v, __shfl_down(v, off, 64));
    int t = threadIdx.x;
    if ((t & 63) == 0) tmp[t >> 6] = v;
    __syncthreads();
    return fmaxf(fmaxf(tmp[0], tmp[1]), fmaxf(tmp[2], tmp[3]));
}

// ---------------- generic batched GEMM via bf16x3-split MFMA ----------------
// C = cdiagc*I - [ alpha * A @ B' (+bias) ]   (transforms optional, += if accum)
// B' = bdiagc*I - B  when btrans (only in Bn==1 path)
// A addr: Abase(bz) + (m+Arow)*Am + k          (k-stride 1)
// B addr: Bbase(bz) + k*Bk + n*Bn              (Bn==1 or Bk==1)
// C addr: Cbase(bz) + (m+Crow)*Cm + n
struct GemmP {
    const float* A; const float* B; float* C; const float* bias;
    long long As1, As2, Bs1, Bs2, Cs1, Cs2;
    int Adiv, Bdiv, Cdiv;
    int Am, Bk, Bn, Cm, Arow, Crow;
    int M, N, K, nb;
    float alpha; int accum;
    float bdiagc; int btrans; float cdiagc; int ctrans;
};

// LDS: A-hi, A-lo, B-hi, B-lo tiles. 64 rows x 32 cols, row stride 40 u16
// (80 B -> 20-bank stride: 2-way aliasing only, and 8 B-aligned for b64 reads).
constexpr int LDSTR = 40;
constexpr int AH = 0, AL = 2560, BH = 5120, BL = 7680;

__global__ __launch_bounds__(256) void gemm_k(GemmP p) {
    __shared__ u16 lds[10240];
    const int bz = blockIdx.z;
    const float* Ab = p.A + (long long)(bz / p.Adiv) * p.As1 + (long long)(bz % p.Adiv) * p.As2;
    const float* Bb = p.B + (long long)(bz / p.Bdiv) * p.Bs1 + (long long)(bz % p.Bdiv) * p.Bs2;
    float*       Cb = p.C + (long long)(bz / p.Cdiv) * p.Cs1 + (long long)(bz % p.Cdiv) * p.Cs2;
    const int m0 = blockIdx.y * 64, n0 = blockIdx.x * 64;
    const int t = threadIdx.x;
    const int wave = t >> 6, lane = t & 63;
    const int wm = (wave & 1) * 32, wn = (wave >> 1) * 32;
    const int quad = lane >> 4, l15 = lane & 15;

    f32x4 acc[2][2];
#pragma unroll
    for (int i = 0; i < 2; ++i)
#pragma unroll
        for (int j = 0; j < 2; ++j) acc[i][j] = (f32x4){0.f, 0.f, 0.f, 0.f};

    for (int k0 = 0; k0 < p.K; k0 += 32) {
        // ---- stage A (64 rows x 32 k), split to bf16 hi/lo ----
        {
            const int ar = t >> 2, ac = (t & 3) * 8;
            float v[8];
            if (m0 + ar < p.M) {
                const float* s = Ab + (long long)(m0 + ar + p.Arow) * p.Am + (k0 + ac);
                float4 x0 = *(const float4*)s, x1 = *(const float4*)(s + 4);
                v[0] = x0.x; v[1] = x0.y; v[2] = x0.z; v[3] = x0.w;
                v[4] = x1.x; v[5] = x1.y; v[6] = x1.z; v[7] = x1.w;
            } else {
#pragma unroll
                for (int i = 0; i < 8; ++i) v[i] = 0.f;
            }
            u16 h[8], l[8];
#pragma unroll
            for (int i = 0; i < 8; ++i) { h[i] = f2bf(v[i]); l[i] = f2bf(v[i] - bf2f(h[i])); }
            const int off = ar * LDSTR + ac;
            u16x4 a0, a1, b0, b1;
#pragma unroll
            for (int i = 0; i < 4; ++i) { a0[i] = h[i]; a1[i] = h[i + 4]; b0[i] = l[i]; b1[i] = l[i + 4]; }
            *(u16x4*)&lds[AH + off] = a0; *(u16x4*)&lds[AH + off + 4] = a1;
            *(u16x4*)&lds[AL + off] = b0; *(u16x4*)&lds[AL + off + 4] = b1;
        }
        // ---- stage B (32 k x 64 n) into n-major LDS [n][k] ----
        if (p.Bn == 1) {   // row-major [k][n] in global: coalesced read, transposed write
            const int bk = t >> 3, n8 = (t & 7) * 8;
            const float* s = Bb + (long long)(k0 + bk) * p.Bk + (n0 + n8);
            float4 x0 = *(const float4*)s, x1 = *(const float4*)(s + 4);
            float v[8] = {x0.x, x0.y, x0.z, x0.w, x1.x, x1.y, x1.z, x1.w};
            if (p.btrans) {
                const int gk = k0 + bk;
#pragma unroll
                for (int i = 0; i < 8; ++i)
                    v[i] = (gk == n0 + n8 + i ? p.bdiagc : 0.f) - v[i];
            }
#pragma unroll
            for (int i = 0; i < 8; ++i) {       // rotation-staggered to spread banks
                int j = (i + (t & 7)) & 7;
                u16 h = f2bf(v[j]);
                lds[BH + (n8 + j) * LDSTR + bk] = h;
                lds[BL + (n8 + j) * LDSTR + bk] = f2bf(v[j] - bf2f(h));
            }
        } else {           // n-major [n][k] in global: direct
            const int bn = t >> 2, k8 = (t & 3) * 8;
            const float* s = Bb + (long long)(n0 + bn) * p.Bn + (k0 + k8);
            float4 x0 = *(const float4*)s, x1 = *(const float4*)(s + 4);
            float v[8] = {x0.x, x0.y, x0.z, x0.w, x1.x, x1.y, x1.z, x1.w};
            u16 h[8], l[8];
#pragma unroll
            for (int i = 0; i < 8; ++i) { h[i] = f2bf(v[i]); l[i] = f2bf(v[i] - bf2f(h[i])); }
            const int off = bn * LDSTR + k8;
            u16x4 a0, a1, b0, b1;
#pragma unroll
            for (int i = 0; i < 4; ++i) { a0[i] = h[i]; a1[i] = h[i + 4]; b0[i] = l[i]; b1[i] = l[i + 4]; }
            *(u16x4*)&lds[BH + off] = a0; *(u16x4*)&lds[BH + off + 4] = a1;
            *(u16x4*)&lds[BL + off] = b0; *(u16x4*)&lds[BL + off + 4] = b1;
        }
        __syncthreads();

        // ---- fragments + 12 MFMA ----
        s16x8 ah[2], al[2], bh[2], bl[2];
#pragma unroll
        for (int mi = 0; mi < 2; ++mi) {
            const int off = (wm + mi * 16 + l15) * LDSTR + quad * 8;
            u16x4 q0 = *(const u16x4*)&lds[AH + off], q1 = *(const u16x4*)&lds[AH + off + 4];
            u16x4 r0 = *(const u16x4*)&lds[AL + off], r1 = *(const u16x4*)&lds[AL + off + 4];
            s16x8 fh, fl;
#pragma unroll
            for (int i = 0; i < 4; ++i) { fh[i] = q0[i]; fh[i + 4] = q1[i]; fl[i] = r0[i]; fl[i + 4] = r1[i]; }
            ah[mi] = fh; al[mi] = fl;
        }
#pragma unroll
        for (int ni = 0; ni < 2; ++ni) {
            const int off = (wn + ni * 16 + l15) * LDSTR + quad * 8;
            u16x4 q0 = *(const u16x4*)&lds[BH + off], q1 = *(const u16x4*)&lds[BH + off + 4];
            u16x4 r0 = *(const u16x4*)&lds[BL + off], r1 = *(const u16x4*)&lds[BL + off + 4];
            s16x8 fh, fl;
#pragma unroll
            for (int i = 0; i < 4; ++i) { fh[i] = q0[i]; fh[i + 4] = q1[i]; fl[i] = r0[i]; fl[i + 4] = r1[i]; }
            bh[ni] = fh; bl[ni] = fl;
        }
#pragma unroll
        for (int mi = 0; mi < 2; ++mi)
#pragma unroll
            for (int ni = 0; ni < 2; ++ni) {
                acc[mi][ni] = __builtin_amdgcn_mfma_f32_16x16x32_bf16(ah[mi], bh[ni], acc[mi][ni], 0, 0, 0);
                acc[mi][ni] = __builtin_amdgcn_mfma_f32_16x16x32_bf16(ah[mi], bl[ni], acc[mi][ni], 0, 0, 0);
                acc[mi][ni] = __builtin_amdgcn_mfma_f32_16x16x32_bf16(al[mi], bh[ni], acc[mi][ni], 0, 0, 0);
            }
        __syncthreads();
    }

    // ---- epilogue: C/D layout col=lane&15, row=quad*4+reg ----
#pragma unroll
    for (int mi = 0; mi < 2; ++mi)
#pragma unroll
        for (int ni = 0; ni < 2; ++ni) {
            const int n = n0 + wn + ni * 16 + l15;
#pragma unroll
            for (int r = 0; r < 4; ++r) {
                const int m = m0 + wm + mi * 16 + quad * 4 + r;
                if (m >= p.M) continue;
                float v = p.alpha * acc[mi][ni][r];
                if (p.bias) v += p.bias[n];
                if (p.ctrans) v = (m == n ? p.cdiagc : 0.f) - v;
                float* dst = Cb + (long long)(m + p.Crow) * p.Cm + n;
                if (p.accum) *dst += v; else *dst = v;
            }
        }
}

// ---------------- small kernels ----------------
__global__ void cls_set_k(float* H0, const float* cls) {
    int t = blockIdx.x * 256 + threadIdx.x; // 8*512
    int b = t >> 9, c = t & 511;
    H0[(long long)b * NTOK * EMBD + c] = cls[c];
}

__global__ __launch_bounds__(256) void ln_pad_k(const float* __restrict__ H0,
                                                float* __restrict__ out,
                                                const float* g, const float* bb) {
    int row = blockIdx.x, b = blockIdx.y, t = threadIdx.x;
    float* o = out + ((long long)b * NP + row) * EMBD;
    if (row < PADR) { o[t] = 0.f; o[t + 256] = 0.f; return; }
    const float* x = H0 + ((long long)b * NTOK + (row - PADR)) * EMBD;
    float v0 = x[t], v1 = x[t + 256];
    float mu = block_sum256(v0 + v1) * (1.f / EMBD);
    float d0 = v0 - mu, d1 = v1 - mu;
    float var = block_sum256(d0 * d0 + d1 * d1) * (1.f / EMBD);
    float rs = 1.f / sqrtf(var + 1e-5f);
    o[t]       = d0 * rs * g[t]       + bb[t];
    o[t + 256] = d1 * rs * g[t + 256] + bb[t + 256];
}

__global__ void landmark_k(const float* __restrict__ QKV, float* __restrict__ QL,
                           float* __restrict__ KL) {
    long long idx = (long long)blockIdx.x * 256 + threadIdx.x; // 32*256*128
    int d = idx & 127; int i = (int)((idx >> 7) & 255); int bh = (int)(idx >> 15);
    int b = bh >> 2, h = bh & 3;
    const float* base = QKV + (long long)b * NP * 1536 + (long long)i * LSUB * 1536 + h * DHD + d;
    float sq = 0.f, sk = 0.f;
#pragma unroll
    for (int j = 0; j < LSUB; ++j) { sq += base[j * 1536]; sk += base[j * 1536 + EMBD]; }
    QL[idx] = sq * (1.f / LSUB);
    KL[idx] = sk * (1.f / LSUB);
}

// wave-per-row softmax for rows of exactly 256 floats
__global__ __launch_bounds__(256) void softmax256_k(float* __restrict__ X) {
    long long row = (long long)blockIdx.x * 4 + (threadIdx.x >> 6);
    int lane = threadIdx.x & 63;
    float4* p = (float4*)(X + row * 256) + lane;
    float4 v = *p;
    float m = fmaxf(fmaxf(v.x, v.y), fmaxf(v.z, v.w));
#pragma unroll
    for (int off = 32; off > 0; off >>= 1) m = fmaxf(m, __shfl_xor(m, off, 64));
    float ex = __expf(v.x - m), ey = __expf(v.y - m), ez = __expf(v.z - m), ew = __expf(v.w - m);
    float s = ex + ey + ez + ew;
#pragma unroll
    for (int off = 32; off > 0; off >>= 1) s += __shfl_xor(s, off, 64);
    float inv = 1.f / s;
    *p = make_float4(ex * inv, ey * inv, ez * inv, ew * inv);
}

// block-per-row softmax, float4 vectorized
__global__ __launch_bounds__(256) void softmax_k(float* __restrict__ X, int L) {
    float4* p = (float4*)(X + (long long)blockIdx.x * L);
    int nv = L >> 2, t = threadIdx.x;
    float m = -1e30f;
    for (int i = t; i < nv; i += 256) {
        float4 v = p[i];
        m = fmaxf(m, fmaxf(fmaxf(v.x, v.y), fmaxf(v.z, v.w)));
    }
    m = block_max256(m);
    float s = 0.f;
    for (int i = t; i < nv; i += 256) {
        float4 v = p[i];
        v.x = __expf(v.x - m); v.y = __expf(v.y - m); v.z = __expf(v.z - m); v.w = __expf(v.w - m);
        p[i] = v;
        s += v.x + v.y + v.z + v.w;
    }
    s = block_sum256(s);
    float inv = 1.f / s;
    for (int i = t; i < nv; i += 256) {
        float4 v = p[i];
        p[i] = make_float4(v.x * inv, v.y * inv, v.z * inv, v.w * inv);
    }
}

__global__ __launch_bounds__(256) void pinv_absmax_k(const float* __restrict__ X, float* red) {
    int bh = blockIdx.x, t = threadIdx.x;
    const float* x = X + (long long)bh * 65536;
    float rs = 0.f, cs = 0.f;
    for (int j = 0; j < 256; ++j) { rs += fabsf(x[t * 256 + j]); cs += fabsf(x[j * 256 + t]); }
    float mr = block_max256(rs);
    float mc = block_max256(cs);
    if (t == 0) { red[bh] = mr; red[32 + bh] = mc; }
}

__global__ void pinv_scalar_k(const float* red, float* inv) {
    float mr = 0.f, mc = 0.f;
    for (int i = 0; i < 32; ++i) { mr = fmaxf(mr, red[i]); mc = fmaxf(mc, red[32 + i]); }
    inv[0] = 1.f / (mr * mc);
}

__global__ void pinv_tinit_k(const float* __restrict__ X, const float* __restrict__ inv,
                             float* __restrict__ Z) {
    long long idx = (long long)blockIdx.x * 256 + threadIdx.x; // 32*65536
    int j = (int)(idx & 255); int i = (int)((idx >> 8) & 255); long long bh = idx >> 16;
    Z[idx] = X[(bh << 16) + ((long long)j << 8) + i] * inv[0];
}

// depthwise residual conv on v (kernel 33 along seq), += into ATT2 (rows PADR..NP-1)
__global__ void resconv_k(const float* __restrict__ QKV, const float* __restrict__ rk,
                          float* __restrict__ ATT2) {
    long long idx = (long long)blockIdx.x * 256 + threadIdx.x; // 8*4097*512
    if (idx >= (long long)BATCH * NTOK * EMBD) return;
    int c = (int)(idx & 511); long long r = idx >> 9;
    int n = PADR + (int)(r % NTOK); int b = (int)(r / NTOK);
    int h = c >> 7, d = c & 127;
    const float* vb = QKV + (long long)b * NP * 1536 + 1024 + h * DHD + d;
    float acc = 0.f;
#pragma unroll
    for (int u = 0; u < 33; ++u) {
        int nn = n + u - 16;
        if (nn >= 0 && nn < NP) acc += vb[(long long)nn * 1536] * rk[h * 33 + u];
    }
    ATT2[((long long)b * NP + n) * EMBD + c] += acc;
}

// PPEG v3: fixed channel per thread, weights register-resident ((256,2) -> 128 VGPRs),
// position unroll x2 for two independent load/FMA chains.
__global__ __launch_bounds__(256, 2) void ppeg2_k(const float* __restrict__ H0,
                                                  const float* __restrict__ k7, const float* __restrict__ b7,
                                                  const float* __restrict__ k5, const float* __restrict__ b5,
                                                  const float* __restrict__ k3, const float* __restrict__ b3,
                                                  float* __restrict__ TMP) {
    const int c = blockIdx.y * 256 + threadIdx.x;
    const int b = blockIdx.z;
    const float* base = H0 + ((long long)b * NTOK + 1) * EMBD + c;
    float w7[49], w5[25], w3[9];
#pragma unroll
    for (int i = 0; i < 49; ++i) w7[i] = k7[c * 49 + i];
#pragma unroll
    for (int i = 0; i < 25; ++i) w5[i] = k5[c * 25 + i];
#pragma unroll
    for (int i = 0; i < 9; ++i)  w3[i] = k3[c * 9 + i];
    const float bias = b7[c] + b5[c] + b3[c];
    float* tb = TMP + ((long long)b * 4096) * EMBD + c;

    const int p0 = blockIdx.x * 128;
    for (int pp = 0; pp < 128; pp += 2) {
        const int pos0 = p0 + pp, pos1 = pos0 + 1;
        const int y0 = pos0 >> 6, x0 = pos0 & 63;
        const int y1 = pos1 >> 6, x1 = pos1 & 63;
        float acc0 = base[(long long)pos0 * EMBD] + bias;
        float acc1 = base[(long long)pos1 * EMBD] + bias;
        const bool int0 = (y0 >= 3 && y0 < 61 && x0 >= 3 && x0 < 61);
        const bool int1 = (y1 >= 3 && y1 < 61 && x1 >= 3 && x1 < 61);
        if (int0 && int1) {
#pragma unroll
            for (int dy = 0; dy < 7; ++dy)
#pragma unroll
                for (int dx = 0; dx < 7; ++dx) {
                    const int o = (dy - 3) * 64 + (dx - 3);
                    const float w = w7[dy * 7 + dx];
                    acc0 += base[(long long)(pos0 + o) * EMBD] * w;
                    acc1 += base[(long long)(pos1 + o) * EMBD] * w;
                }
#pragma unroll
            for (int dy = 0; dy < 5; ++dy)
#pragma unroll
                for (int dx = 0; dx < 5; ++dx) {
                    const int o = (dy - 2) * 64 + (dx - 2);
                    const float w = w5[dy * 5 + dx];
                    acc0 += base[(long long)(pos0 + o) * EMBD] * w;
                    acc1 += base[(long long)(pos1 + o) * EMBD] * w;
                }
#pragma unroll
            for (int dy = 0; dy < 3; ++dy)
#pragma unroll
                for (int dx = 0; dx < 3; ++dx) {
                    const int o = (dy - 1) * 64 + (dx - 1);
                    const float w = w3[dy * 3 + dx];
                    acc0 += base[(long long)(pos0 + o) * EMBD] * w;
                    acc1 += base[(long long)(pos1 + o) * EMBD] * w;
                }
        } else {
#pragma unroll
            for (int dy = 0; dy < 7; ++dy) {
                int ya = y0 + dy - 3, yb = y1 + dy - 3;
#pragma unroll
                for (int dx = 0; dx < 7; ++dx) {
                    const float w = w7[dy * 7 + dx];
                    int xa = x0 + dx - 3, xb = x1 + dx - 3;
                    if ((unsigned)ya < 64u && (unsigned)xa < 64u) acc0 += base[(long long)(ya * 64 + xa) * EMBD] * w;
                    if ((unsigned)yb < 64u && (unsigned)xb < 64u) acc1 += base[(long long)(yb * 64 + xb) * EMBD] * w;
                }
            }
#pragma unroll
            for (int dy = 0; dy < 5; ++dy) {
                int ya = y0 + dy - 2, yb = y1 + dy - 2;
#pragma unroll
                for (int dx = 0; dx < 5; ++dx) {
                    const float w = w5[dy * 5 + dx];
                    int xa = x0 + dx - 2, xb = x1 + dx - 2;
                    if ((unsigned)ya < 64u && (unsigned)xa < 64u) acc0 += base[(long long)(ya * 64 + xa) * EMBD] * w;
                    if ((unsigned)yb < 64u && (unsigned)xb < 64u) acc1 += base[(long long)(yb * 64 + xb) * EMBD] * w;
                }
            }
#pragma unroll
            for (int dy = 0; dy < 3; ++dy) {
                int ya = y0 + dy - 1, yb = y1 + dy - 1;
#pragma unroll
                for (int dx = 0; dx < 3; ++dx) {
                    const float w = w3[dy * 3 + dx];
                    int xa = x0 + dx - 1, xb = x1 + dx - 1;
                    if ((unsigned)ya < 64u && (unsigned)xa < 64u) acc0 += base[(long long)(ya * 64 + xa) * EMBD] * w;
                    if ((unsigned)yb < 64u && (unsigned)xb < 64u) acc1 += base[(long long)(yb * 64 + xb) * EMBD] * w;
                }
            }
        }
        tb[(long long)pos0 * EMBD] = acc0;
        tb[(long long)pos1 * EMBD] = acc1;
    }
}

__global__ void copyback_k(const float* __restrict__ TMP, float* __restrict__ H0) {
    long long idx = (long long)blockIdx.x * 256 + threadIdx.x; // 8*4096*512
    int c = (int)(idx & 511); int pos = (int)((idx >> 9) & 4095); int b = (int)(idx >> 21);
    H0[((long long)b * NTOK + 1 + pos) * EMBD + c] = TMP[idx];
}

__global__ __launch_bounds__(256) void head_k(const float* __restrict__ H0, const float* g,
                                              const float* bb, const float* cw, const float* cb,
                                              float* __restrict__ out) {
    int b = blockIdx.x, t = threadIdx.x;
    const float* x = H0 + (long long)b * NTOK * EMBD;
    float v0 = x[t], v1 = x[t + 256];
    float mu = block_sum256(v0 + v1) * (1.f / EMBD);
    float d0 = v0 - mu, d1 = v1 - mu;
    float var = block_sum256(d0 * d0 + d1 * d1) * (1.f / EMBD);
    float rs = 1.f / sqrtf(var + 1e-5f);
    float y0 = d0 * rs * g[t] + bb[t];
    float y1 = d1 * rs * g[t + 256] + bb[t + 256];
    float s = block_sum256(y0 * cw[t] + y1 * cw[t + 256]);
    if (t == 0) out[b] = s + cb[0];
}

// ---------------- host orchestration ----------------
extern "C" void kernel_launch(void* const* d_in, const int* in_sizes, int n_in,
                              void* d_out, int out_size, void* d_ws, size_t ws_size,
                              hipStream_t stream) {
    (void)in_sizes; (void)n_in; (void)out_size; (void)ws_size;
    const float* X        = (const float*)d_in[0];
    const float* few_w    = (const float*)d_in[1];
    const float* few_b    = (const float*)d_in[2];
    const float* cls_tok  = (const float*)d_in[3];
    const float* ln_g[2]  = {(const float*)d_in[4],  (const float*)d_in[10]};
    const float* ln_b[2]  = {(const float*)d_in[5],  (const float*)d_in[11]};
    const float* qkv_w[2] = {(const float*)d_in[6],  (const float*)d_in[12]};
    const float* out_w[2] = {(const float*)d_in[7],  (const float*)d_in[13]};
    const float* out_b[2] = {(const float*)d_in[8],  (const float*)d_in[14]};
    const float* res_k[2] = {(const float*)d_in[9],  (const float*)d_in[15]};
    const float* k7 = (const float*)d_in[16]; const float* b7 = (const float*)d_in[17];
    const float* k5 = (const float*)d_in[18]; const float* b5 = (const float*)d_in[19];
    const float* k3 = (const float*)d_in[20]; const float* b3 = (const float*)d_in[21];
    const float* norm_g = (const float*)d_in[22]; const float* norm_b = (const float*)d_in[23];
    const float* cls_w  = (const float*)d_in[24]; const float* cls_b  = (const float*)d_in[25];
    float* out = (float*)d_out;

    // workspace layout (floats)
    float* ws  = (float*)d_ws;
    float* H0  = ws;                         // 8*4097*512
    float* LNH = H0  + 16781312LL;           // 8*4352*512   (also ATT2)
    float* QKV = LNH + 17825792LL;           // 8*4352*1536  (also PPEG TMP)
    float* A3  = QKV + 53477376LL;           // 32*256*4352  (also A1 / pinv temps)
    float* QL  = A3  + 35651584LL;
    float* KL  = QL  + 1048576LL;
    float* A2  = KL  + 1048576LL;
    float* KV  = A2  + 2097152LL;
    float* ZKV = KV  + 1048576LL;
    float* RED = ZKV + 1048576LL;
    float* Zb0 = A3;                 // pinv temps overlay A3 (dead after KV gemm)
    float* Zb1 = A3 + 2097152LL;
    float* XZm = A3 + 4194304LL;

    auto gemmx = [&](const float* A, long long As1, long long As2, int Adiv, int Am, int Arow,
                     const float* Bm, long long Bs1, long long Bs2, int Bdiv, int Bk, int Bn,
                     float* C, long long Cs1, long long Cs2, int Cdiv, int Cm, int Crow,
                     int M, int N, int K, int nb, float alpha, int accum, const float* bias,
                     float bdiagc, int btrans, float cdiagc, int ctrans) {
        GemmP p;
        p.A = A; p.B = Bm; p.C = C; p.bias = bias;
        p.As1 = As1; p.As2 = As2; p.Bs1 = Bs1; p.Bs2 = Bs2; p.Cs1 = Cs1; p.Cs2 = Cs2;
        p.Adiv = Adiv; p.Bdiv = Bdiv; p.Cdiv = Cdiv;
        p.Am = Am; p.Bk = Bk; p.Bn = Bn; p.Cm = Cm; p.Arow = Arow; p.Crow = Crow;
        p.M = M; p.N = N; p.K = K; p.nb = nb; p.alpha = alpha; p.accum = accum;
        p.bdiagc = bdiagc; p.btrans = btrans; p.cdiagc = cdiagc; p.ctrans = ctrans;
        dim3 grid(N / 64, (M + 63) / 64, nb);
        gemm_k<<<grid, 256, 0, stream>>>(p);
    };
    auto gemm = [&](const float* A, long long As1, long long As2, int Adiv, int Am, int Arow,
                    const float* Bm, long long Bs1, long long Bs2, int Bdiv, int Bk, int Bn,
                    float* C, long long Cs1, long long Cs2, int Cdiv, int Cm, int Crow,
                    int M, int N, int K, int nb, float alpha, int accum, const float* bias) {
        gemmx(A, As1, As2, Adiv, Am, Arow, Bm, Bs1, Bs2, Bdiv, Bk, Bn,
              C, Cs1, Cs2, Cdiv, Cm, Crow, M, N, K, nb, alpha, accum, bias, 0.f, 0, 0.f, 0);
    };

    // ---- stem: cls token + few-shot linear ----
    cls_set_k<<<16, 256, 0, stream>>>(H0, cls_tok);
    gemm(X, 4194304LL, 0, 1, 1024, 0,
         few_w, 0, 0, 1, 512, 1,
         H0, 2097664LL, 0, 1, 512, 1,
         4096, 512, 1024, BATCH, 1.f, 0, few_b);

    for (int L = 0; L < 2; ++L) {
        ln_pad_k<<<dim3(NP, BATCH), 256, 0, stream>>>(H0, LNH, ln_g[L], ln_b[L]);
        gemm(LNH, 0, 0, 1, 512, 0,
             qkv_w[L], 0, 0, 1, 1536, 1,
             QKV, 0, 0, 1, 1536, 0,
             BATCH * NP, 1536, 512, 1, 1.f, 0, nullptr);
        landmark_k<<<4096, 256, 0, stream>>>(QKV, QL, KL);
        // a2 = softmax(SCALE * QL @ KL^T)
        gemm(QL, 32768LL, 0, 1, 128, 0,
             KL, 32768LL, 0, 1, 1, 128,
             A2, 65536LL, 0, 1, 256, 0,
             256, 256, 128, 32, SCALE_F, 0, nullptr);
        softmax256_k<<<2048, 256, 0, stream>>>(A2);
        // a3 = softmax(SCALE * QL @ K^T)
        gemm(QL, 32768LL, 0, 1, 128, 0,
             QKV + 512, 6680064LL, 128LL, 4, 1, 1536,
             A3, 1114112LL, 0, 1, 4352, 0,
             256, 4352, 128, 32, SCALE_F, 0, nullptr);
        softmax_k<<<8192, 256, 0, stream>>>(A3, 4352);
        // KV = a3 @ V
        gemm(A3, 1114112LL, 0, 1, 4352, 0,
             QKV + 1024, 6680064LL, 128LL, 4, 1536, 1,
             KV, 32768LL, 0, 1, 128, 0,
             256, 128, 4352, 32, 1.f, 0, nullptr);
        // pinv(a2): global-scalar init, then 6 Newton iterations (4 fused gemms each)
        pinv_absmax_k<<<32, 256, 0, stream>>>(A2, RED);
        pinv_scalar_k<<<1, 1, 0, stream>>>(RED, RED + 64);
        pinv_tinit_k<<<8192, 256, 0, stream>>>(A2, RED + 64, Zb0);
        float* zc = Zb0; float* zn = Zb1;
        for (int it = 0; it < 6; ++it) {
            float* U1 = A3 + 6291456LL;  // scratch
            float* U2 = A3 + 8388608LL;
            // P = A2 @ zc
            gemm(A2, 65536LL, 0, 1, 256, 0, zc, 65536LL, 0, 1, 256, 1,
                 XZm, 65536LL, 0, 1, 256, 0, 256, 256, 256, 32, 1.f, 0, nullptr);
            // U1 = 15I - P @ (7I - P)
            gemmx(XZm, 65536LL, 0, 1, 256, 0, XZm, 65536LL, 0, 1, 256, 1,
                  U1, 65536LL, 0, 1, 256, 0, 256, 256, 256, 32, 1.f, 0, nullptr,
                  7.f, 1, 15.f, 1);
            // U2 = 13I - P @ U1
            gemmx(XZm, 65536LL, 0, 1, 256, 0, U1, 65536LL, 0, 1, 256, 1,
                  U2, 65536LL, 0, 1, 256, 0, 256, 256, 256, 32, 1.f, 0, nullptr,
                  0.f, 0, 13.f, 1);
            // zn = 0.25 * zc @ U2
            gemm(zc, 65536LL, 0, 1, 256, 0, U2, 65536LL, 0, 1, 256, 1,
                 zn, 65536LL, 0, 1, 256, 0, 256, 256, 256, 32, 0.25f, 0, nullptr);
            float* t2 = zc; zc = zn; zn = t2;
        }
        // ZKV = pinv @ KV
        gemm(zc, 65536LL, 0, 1, 256, 0,
             KV, 32768LL, 0, 1, 128, 1,
             ZKV, 32768LL, 0, 1, 128, 0,
             256, 128, 256, 32, 1.f, 0, nullptr);
        // a1 = softmax(SCALE * Q @ KL^T)
        gemm(QKV, 6680064LL, 128LL, 4, 1536, 0,
             KL, 32768LL, 0, 1, 1, 128,
             A3, 1114112LL, 0, 1, 256, 0,
             4352, 256, 128, 32, SCALE_F, 0, nullptr);
        softmax256_k<<<34816, 256, 0, stream>>>(A3);
        // ATT2 = a1 @ ZKV
        gemm(A3, 1114112LL, 0, 1, 256, 0,
             ZKV, 32768LL, 0, 1, 128, 1,
             LNH, 2228224LL, 128LL, 4, 512, 0,
             4352, 128, 256, 32, 1.f, 0, nullptr);
        resconv_k<<<65552, 256, 0, stream>>>(QKV, res_k[L], LNH);
        // H0 += ATT2[PADR:] @ out_w + out_b
        gemm(LNH, 2228224LL, 0, 1, 512, PADR,
             out_w[L], 0, 0, 1, 512, 1,
             H0, 2097664LL, 0, 1, 512, 0,
             NTOK, 512, 512, BATCH, 1.f, 1, out_b[L]);

        if (L == 0) {
            ppeg2_k<<<dim3(32, 2, 8), 256, 0, stream>>>(H0, k7, b7, k5, b5, k3, b3, QKV);
            copyback_k<<<65536, 256, 0, stream>>>(QKV, H0);
        }
    }

    head_k<<<BATCH, 256, 0, stream>>>(H0, norm_g, norm_b, cls_w, cls_b, out);
}

// Round 4
// 4566.313 us; speedup vs baseline: 2.2909x; 1.2907x over previous
//
#include <hip/hip_runtime.h>

// ---------------- constants ----------------
constexpr int BATCH = 8;
constexpr int NTOK  = 4097;   // 1 cls + 4096 tokens
constexpr int NP    = 4352;   // padded seq len (multiple of 256)
constexpr int PADR  = 255;    // zero rows prepended
constexpr int EMBD  = 512;
constexpr int DHD   = 128;
constexpr int LSUB  = 17;     // NP / 256 landmarks
constexpr float SCALE_F = 0.08838834764831845f; // 128^-0.5

// PPEG padded plane: 70 rows x stride 72 (3-halo around 64x64), zeroed borders
constexpr int PPS   = 72;          // row stride
constexpr int PPLN  = 72 * 70;     // plane floats = 5040
constexpr long long TPAD_FLOATS = (long long)BATCH * EMBD * PPLN;   // 20,643,840

typedef unsigned short u16;
typedef short   s16x8 __attribute__((ext_vector_type(8)));
typedef u16     u16x4 __attribute__((ext_vector_type(4)));
typedef float   f32x4 __attribute__((ext_vector_type(4)));

__device__ __forceinline__ u16 f2bf(float x) {   // fp32 -> bf16 bits, RNE
    unsigned u = __float_as_uint(x);
    u += 0x7fffu + ((u >> 16) & 1u);
    return (u16)(u >> 16);
}
__device__ __forceinline__ float bf2f(u16 h) {
    return __uint_as_float(((unsigned)h) << 16);
}

// ---------------- block reductions (blockDim == 256) ----------------
__device__ __forceinline__ float block_sum256(float v) {
    __shared__ float tmp[4];
    __syncthreads();
#pragma unroll
    for (int off = 32; off > 0; off >>= 1) v += __shfl_down(v, off, 64);
    int t = threadIdx.x;
    if ((t & 63) == 0) tmp[t >> 6] = v;
    __syncthreads();
    return tmp[0] + tmp[1] + tmp[2] + tmp[3];
}

__device__ __forceinline__ float block_max256(float v) {
    __shared__ float tmp[4];
    __syncthreads();
#pragma unroll
    for (int off = 32; off > 0; off >>= 1) v = fmaxf(v, __shfl_down(v, off, 64));
    int t = threadIdx.x;
    if ((t & 63) == 0) tmp[t >> 6] = v;
    __syncthreads();
    return fmaxf(fmaxf(tmp[0], tmp[1]), fmaxf(tmp[2], tmp[3]));
}

// ---------------- generic batched GEMM via bf16x3-split MFMA ----------------
// C = cdiagc*I - [ alpha * A @ B' (+bias) ]   (transforms optional, += if accum)
// B' = bdiagc*I - B  when btrans (only in Bn==1 path)
struct GemmP {
    const float* A; const float* B; float* C; const float* bias;
    long long As1, As2, Bs1, Bs2, Cs1, Cs2;
    int Adiv, Bdiv, Cdiv;
    int Am, Bk, Bn, Cm, Arow, Crow;
    int M, N, K, nb;
    float alpha; int accum;
    float bdiagc; int btrans; float cdiagc; int ctrans;
};

// LDS: A-hi, A-lo, B-hi, B-lo tiles. 64 rows x 32 cols, row stride 40 u16.
constexpr int LDSTR = 40;
constexpr int AH = 0, AL = 2560, BHs = 5120, BLs = 7680;

__global__ __launch_bounds__(256) void gemm_k(GemmP p) {
    __shared__ u16 lds[10240];
    const int bz = blockIdx.z;
    const float* Ab = p.A + (long long)(bz / p.Adiv) * p.As1 + (long long)(bz % p.Adiv) * p.As2;
    const float* Bb = p.B + (long long)(bz / p.Bdiv) * p.Bs1 + (long long)(bz % p.Bdiv) * p.Bs2;
    float*       Cb = p.C + (long long)(bz / p.Cdiv) * p.Cs1 + (long long)(bz % p.Cdiv) * p.Cs2;
    const int m0 = blockIdx.y * 64, n0 = blockIdx.x * 64;
    const int t = threadIdx.x;
    const int wave = t >> 6, lane = t & 63;
    const int wm = (wave & 1) * 32, wn = (wave >> 1) * 32;
    const int quad = lane >> 4, l15 = lane & 15;

    f32x4 acc[2][2];
#pragma unroll
    for (int i = 0; i < 2; ++i)
#pragma unroll
        for (int j = 0; j < 2; ++j) acc[i][j] = (f32x4){0.f, 0.f, 0.f, 0.f};

    for (int k0 = 0; k0 < p.K; k0 += 32) {
        {
            const int ar = t >> 2, ac = (t & 3) * 8;
            float v[8];
            if (m0 + ar < p.M) {
                const float* s = Ab + (long long)(m0 + ar + p.Arow) * p.Am + (k0 + ac);
                float4 x0 = *(const float4*)s, x1 = *(const float4*)(s + 4);
                v[0] = x0.x; v[1] = x0.y; v[2] = x0.z; v[3] = x0.w;
                v[4] = x1.x; v[5] = x1.y; v[6] = x1.z; v[7] = x1.w;
            } else {
#pragma unroll
                for (int i = 0; i < 8; ++i) v[i] = 0.f;
            }
            u16 h[8], l[8];
#pragma unroll
            for (int i = 0; i < 8; ++i) { h[i] = f2bf(v[i]); l[i] = f2bf(v[i] - bf2f(h[i])); }
            const int off = ar * LDSTR + ac;
            u16x4 a0, a1, b0, b1;
#pragma unroll
            for (int i = 0; i < 4; ++i) { a0[i] = h[i]; a1[i] = h[i + 4]; b0[i] = l[i]; b1[i] = l[i + 4]; }
            *(u16x4*)&lds[AH + off] = a0; *(u16x4*)&lds[AH + off + 4] = a1;
            *(u16x4*)&lds[AL + off] = b0; *(u16x4*)&lds[AL + off + 4] = b1;
        }
        if (p.Bn == 1) {   // row-major [k][n]: coalesced read, transposed write
            const int bk = t >> 3, n8 = (t & 7) * 8;
            const float* s = Bb + (long long)(k0 + bk) * p.Bk + (n0 + n8);
            float4 x0 = *(const float4*)s, x1 = *(const float4*)(s + 4);
            float v[8] = {x0.x, x0.y, x0.z, x0.w, x1.x, x1.y, x1.z, x1.w};
            if (p.btrans) {
                const int gk = k0 + bk;
#pragma unroll
                for (int i = 0; i < 8; ++i)
                    v[i] = (gk == n0 + n8 + i ? p.bdiagc : 0.f) - v[i];
            }
#pragma unroll
            for (int i = 0; i < 8; ++i) {
                int j = (i + (t & 7)) & 7;
                u16 h = f2bf(v[j]);
                lds[BHs + (n8 + j) * LDSTR + bk] = h;
                lds[BLs + (n8 + j) * LDSTR + bk] = f2bf(v[j] - bf2f(h));
            }
        } else {           // n-major [n][k]: direct
            const int bn = t >> 2, k8 = (t & 3) * 8;
            const float* s = Bb + (long long)(n0 + bn) * p.Bn + (k0 + k8);
            float4 x0 = *(const float4*)s, x1 = *(const float4*)(s + 4);
            float v[8] = {x0.x, x0.y, x0.z, x0.w, x1.x, x1.y, x1.z, x1.w};
            u16 h[8], l[8];
#pragma unroll
            for (int i = 0; i < 8; ++i) { h[i] = f2bf(v[i]); l[i] = f2bf(v[i] - bf2f(h[i])); }
            const int off = bn * LDSTR + k8;
            u16x4 a0, a1, b0, b1;
#pragma unroll
            for (int i = 0; i < 4; ++i) { a0[i] = h[i]; a1[i] = h[i + 4]; b0[i] = l[i]; b1[i] = l[i + 4]; }
            *(u16x4*)&lds[BHs + off] = a0; *(u16x4*)&lds[BHs + off + 4] = a1;
            *(u16x4*)&lds[BLs + off] = b0; *(u16x4*)&lds[BLs + off + 4] = b1;
        }
        __syncthreads();

        s16x8 ah[2], al[2], bh[2], bl[2];
#pragma unroll
        for (int mi = 0; mi < 2; ++mi) {
            const int off = (wm + mi * 16 + l15) * LDSTR + quad * 8;
            u16x4 q0 = *(const u16x4*)&lds[AH + off], q1 = *(const u16x4*)&lds[AH + off + 4];
            u16x4 r0 = *(const u16x4*)&lds[AL + off], r1 = *(const u16x4*)&lds[AL + off + 4];
            s16x8 fh, fl;
#pragma unroll
            for (int i = 0; i < 4; ++i) { fh[i] = q0[i]; fh[i + 4] = q1[i]; fl[i] = r0[i]; fl[i + 4] = r1[i]; }
            ah[mi] = fh; al[mi] = fl;
        }
#pragma unroll
        for (int ni = 0; ni < 2; ++ni) {
            const int off = (wn + ni * 16 + l15) * LDSTR + quad * 8;
            u16x4 q0 = *(const u16x4*)&lds[BHs + off], q1 = *(const u16x4*)&lds[BHs + off + 4];
            u16x4 r0 = *(const u16x4*)&lds[BLs + off], r1 = *(const u16x4*)&lds[BLs + off + 4];
            s16x8 fh, fl;
#pragma unroll
            for (int i = 0; i < 4; ++i) { fh[i] = q0[i]; fh[i + 4] = q1[i]; fl[i] = r0[i]; fl[i + 4] = r1[i]; }
            bh[ni] = fh; bl[ni] = fl;
        }
#pragma unroll
        for (int mi = 0; mi < 2; ++mi)
#pragma unroll
            for (int ni = 0; ni < 2; ++ni) {
                acc[mi][ni] = __builtin_amdgcn_mfma_f32_16x16x32_bf16(ah[mi], bh[ni], acc[mi][ni], 0, 0, 0);
                acc[mi][ni] = __builtin_amdgcn_mfma_f32_16x16x32_bf16(ah[mi], bl[ni], acc[mi][ni], 0, 0, 0);
                acc[mi][ni] = __builtin_amdgcn_mfma_f32_16x16x32_bf16(al[mi], bh[ni], acc[mi][ni], 0, 0, 0);
            }
        __syncthreads();
    }

#pragma unroll
    for (int mi = 0; mi < 2; ++mi)
#pragma unroll
        for (int ni = 0; ni < 2; ++ni) {
            const int n = n0 + wn + ni * 16 + l15;
#pragma unroll
            for (int r = 0; r < 4; ++r) {
                const int m = m0 + wm + mi * 16 + quad * 4 + r;
                if (m >= p.M) continue;
                float v = p.alpha * acc[mi][ni][r];
                if (p.bias) v += p.bias[n];
                if (p.ctrans) v = (m == n ? p.cdiagc : 0.f) - v;
                float* dst = Cb + (long long)(m + p.Crow) * p.Cm + n;
                if (p.accum) *dst += v; else *dst = v;
            }
        }
}

// ---------------- small kernels ----------------
__global__ void cls_set_k(float* H0, const float* cls) {
    int t = blockIdx.x * 256 + threadIdx.x; // 8*512
    int b = t >> 9, c = t & 511;
    H0[(long long)b * NTOK * EMBD + c] = cls[c];
}

__global__ __launch_bounds__(256) void ln_pad_k(const float* __restrict__ H0,
                                                float* __restrict__ out,
                                                const float* g, const float* bb) {
    int row = blockIdx.x, b = blockIdx.y, t = threadIdx.x;
    float* o = out + ((long long)b * NP + row) * EMBD;
    if (row < PADR) { o[t] = 0.f; o[t + 256] = 0.f; return; }
    const float* x = H0 + ((long long)b * NTOK + (row - PADR)) * EMBD;
    float v0 = x[t], v1 = x[t + 256];
    float mu = block_sum256(v0 + v1) * (1.f / EMBD);
    float d0 = v0 - mu, d1 = v1 - mu;
    float var = block_sum256(d0 * d0 + d1 * d1) * (1.f / EMBD);
    float rs = 1.f / sqrtf(var + 1e-5f);
    o[t]       = d0 * rs * g[t]       + bb[t];
    o[t + 256] = d1 * rs * g[t + 256] + bb[t + 256];
}

__global__ void landmark_k(const float* __restrict__ QKV, float* __restrict__ QL,
                           float* __restrict__ KL) {
    long long idx = (long long)blockIdx.x * 256 + threadIdx.x; // 32*256*128
    int d = idx & 127; int i = (int)((idx >> 7) & 255); int bh = (int)(idx >> 15);
    int b = bh >> 2, h = bh & 3;
    const float* base = QKV + (long long)b * NP * 1536 + (long long)i * LSUB * 1536 + h * DHD + d;
    float sq = 0.f, sk = 0.f;
#pragma unroll
    for (int j = 0; j < LSUB; ++j) { sq += base[j * 1536]; sk += base[j * 1536 + EMBD]; }
    QL[idx] = sq * (1.f / LSUB);
    KL[idx] = sk * (1.f / LSUB);
}

// wave-per-row softmax for rows of exactly 256 floats
__global__ __launch_bounds__(256) void softmax256_k(float* __restrict__ X) {
    long long row = (long long)blockIdx.x * 4 + (threadIdx.x >> 6);
    int lane = threadIdx.x & 63;
    float4* p = (float4*)(X + row * 256) + lane;
    float4 v = *p;
    float m = fmaxf(fmaxf(v.x, v.y), fmaxf(v.z, v.w));
#pragma unroll
    for (int off = 32; off > 0; off >>= 1) m = fmaxf(m, __shfl_xor(m, off, 64));
    float ex = __expf(v.x - m), ey = __expf(v.y - m), ez = __expf(v.z - m), ew = __expf(v.w - m);
    float s = ex + ey + ez + ew;
#pragma unroll
    for (int off = 32; off > 0; off >>= 1) s += __shfl_xor(s, off, 64);
    float inv = 1.f / s;
    *p = make_float4(ex * inv, ey * inv, ez * inv, ew * inv);
}

// block-per-row softmax, float4 vectorized
__global__ __launch_bounds__(256) void softmax_k(float* __restrict__ X, int L) {
    float4* p = (float4*)(X + (long long)blockIdx.x * L);
    int nv = L >> 2, t = threadIdx.x;
    float m = -1e30f;
    for (int i = t; i < nv; i += 256) {
        float4 v = p[i];
        m = fmaxf(m, fmaxf(fmaxf(v.x, v.y), fmaxf(v.z, v.w)));
    }
    m = block_max256(m);
    float s = 0.f;
    for (int i = t; i < nv; i += 256) {
        float4 v = p[i];
        v.x = __expf(v.x - m); v.y = __expf(v.y - m); v.z = __expf(v.z - m); v.w = __expf(v.w - m);
        p[i] = v;
        s += v.x + v.y + v.z + v.w;
    }
    s = block_sum256(s);
    float inv = 1.f / s;
    for (int i = t; i < nv; i += 256) {
        float4 v = p[i];
        p[i] = make_float4(v.x * inv, v.y * inv, v.z * inv, v.w * inv);
    }
}

__global__ __launch_bounds__(256) void pinv_absmax_k(const float* __restrict__ X, float* red) {
    int bh = blockIdx.x, t = threadIdx.x;
    const float* x = X + (long long)bh * 65536;
    float rs = 0.f, cs = 0.f;
    for (int j = 0; j < 256; ++j) { rs += fabsf(x[t * 256 + j]); cs += fabsf(x[j * 256 + t]); }
    float mr = block_max256(rs);
    float mc = block_max256(cs);
    if (t == 0) { red[bh] = mr; red[32 + bh] = mc; }
}

__global__ void pinv_scalar_k(const float* red, float* inv) {
    float mr = 0.f, mc = 0.f;
    for (int i = 0; i < 32; ++i) { mr = fmaxf(mr, red[i]); mc = fmaxf(mc, red[32 + i]); }
    inv[0] = 1.f / (mr * mc);
}

__global__ void pinv_tinit_k(const float* __restrict__ X, const float* __restrict__ inv,
                             float* __restrict__ Z) {
    long long idx = (long long)blockIdx.x * 256 + threadIdx.x; // 32*65536
    int j = (int)(idx & 255); int i = (int)((idx >> 8) & 255); long long bh = idx >> 16;
    Z[idx] = X[(bh << 16) + ((long long)j << 8) + i] * inv[0];
}

// depthwise residual conv on v (kernel 33 along seq), += into ATT2 (rows PADR..NP-1)
__global__ void resconv_k(const float* __restrict__ QKV, const float* __restrict__ rk,
                          float* __restrict__ ATT2) {
    long long idx = (long long)blockIdx.x * 256 + threadIdx.x; // 8*4097*512
    if (idx >= (long long)BATCH * NTOK * EMBD) return;
    int c = (int)(idx & 511); long long r = idx >> 9;
    int n = PADR + (int)(r % NTOK); int b = (int)(r / NTOK);
    int h = c >> 7, d = c & 127;
    const float* vb = QKV + (long long)b * NP * 1536 + 1024 + h * DHD + d;
    float acc = 0.f;
#pragma unroll
    for (int u = 0; u < 33; ++u) {
        int nn = n + u - 16;
        if (nn >= 0 && nn < NP) acc += vb[(long long)nn * 1536] * rk[h * 33 + u];
    }
    ATT2[((long long)b * NP + n) * EMBD + c] += acc;
}

// ---------------- PPEG v4: channel-major L1-resident stencil ----------------
// combined 7x7 weights: W = k7 + pad(k5) + pad(k3); bias = b7+b5+b3
__global__ void wsum_k(const float* __restrict__ k7, const float* __restrict__ k5,
                       const float* __restrict__ k3, const float* __restrict__ b7,
                       const float* __restrict__ b5, const float* __restrict__ b3,
                       float* __restrict__ W) {
    int idx = blockIdx.x * 256 + threadIdx.x;
    if (idx < 25088) {
        int c = idx / 49, i = idx - c * 49;
        int dy = i / 7, dx = i - dy * 7;
        float w = k7[idx];
        if (dy >= 1 && dy <= 5 && dx >= 1 && dx <= 5) w += k5[c * 25 + (dy - 1) * 5 + (dx - 1)];
        if (dy >= 2 && dy <= 4 && dx >= 2 && dx <= 4) w += k3[c * 9 + (dy - 2) * 3 + (dx - 2)];
        W[idx] = w;
    } else if (idx < 25600) {
        int c = idx - 25088;
        W[25088 + c] = b7[c] + b5[c] + b3[c];
    }
}

// transpose-in: H0[b,1+pos,c] -> Tpad[(b*512+c)*PPLN + (3+y)*PPS + 3+x]
__global__ __launch_bounds__(256) void tin_k(const float* __restrict__ H0,
                                             float* __restrict__ Tpad) {
    __shared__ float lds[64][65];
    const int y = blockIdx.x, c0 = blockIdx.y * 64, b = blockIdx.z;
    const int t = threadIdx.x;
    const int pc = t & 63, pr4 = t >> 6;
    const float* src = H0 + ((long long)b * NTOK + 1 + y * 64) * EMBD + c0;
#pragma unroll
    for (int i = 0; i < 16; ++i) {
        int pr = pr4 + i * 4;
        lds[pr][pc] = src[(long long)pr * EMBD + pc];
    }
    __syncthreads();
    const int xw = t & 63, cw4 = t >> 6;
#pragma unroll
    for (int i = 0; i < 16; ++i) {
        int cw = cw4 + i * 4;
        Tpad[(long long)(b * 512 + c0 + cw) * PPLN + (3 + y) * PPS + 3 + xw] = lds[xw][cw];
    }
}

// 7x7 conv over one (b,c) plane, rolling register window, 16-row strip per thread-band
__global__ __launch_bounds__(256, 4) void conv7_k(const float* __restrict__ Tpad,
                                                  const float* __restrict__ Wall,
                                                  float* __restrict__ Tout) {
    const int bc = blockIdx.x;            // b*512 + c
    const int c = bc & 511;
    const int t = threadIdx.x;
    const int x = t & 63, band = t >> 6;  // 4 bands of 16 rows
    const int y0 = band * 16;
    const float* in = Tpad + (long long)bc * PPLN + x;   // col offset folded
    float* outp = Tout + (long long)bc * 4096 + x;

    float W[49];
#pragma unroll
    for (int i = 0; i < 49; ++i) W[i] = Wall[c * 49 + i];
    const float bias = Wall[25088 + c];

    float win[7][7];
#pragma unroll
    for (int j = 0; j < 6; ++j)           // preload rows y0-3 .. y0+2 (padded idx y0+j)
#pragma unroll
        for (int d = 0; d < 7; ++d)
            win[j][d] = in[(y0 + j) * PPS + d];

#pragma unroll
    for (int yy = 0; yy < 16; ++yy) {
        const int slot = (6 + yy) % 7;    // row y0+yy+3 (padded idx y0+yy+6)
#pragma unroll
        for (int d = 0; d < 7; ++d)
            win[slot][d] = in[(y0 + yy + 6) * PPS + d];
        float s = bias + win[(yy + 3) % 7][3];   // identity term = center
#pragma unroll
        for (int dy = 0; dy < 7; ++dy) {
            const int r = (yy + dy) % 7;
#pragma unroll
            for (int dx = 0; dx < 7; ++dx)
                s += W[dy * 7 + dx] * win[r][dx];
        }
        outp[(y0 + yy) * 64] = s;
    }
}

// transpose-out: Tout[(b*512+c)*4096 + pos] -> H0[b,1+pos,c]
__global__ __launch_bounds__(256) void tout_k(const float* __restrict__ Tout,
                                              float* __restrict__ H0) {
    __shared__ float lds[64][65];
    const int y = blockIdx.x, c0 = blockIdx.y * 64, b = blockIdx.z;
    const int t = threadIdx.x;
    const int xl = t & 63, cl4 = t >> 6;
#pragma unroll
    for (int i = 0; i < 16; ++i) {
        int cl = cl4 + i * 4;
        lds[xl][cl] = Tout[(long long)(b * 512 + c0 + cl) * 4096 + y * 64 + xl];
    }
    __syncthreads();
    const int pc = t & 63, pl4 = t >> 6;
    float* dst = H0 + ((long long)b * NTOK + 1 + y * 64) * EMBD + c0;
#pragma unroll
    for (int i = 0; i < 16; ++i) {
        int pl = pl4 + i * 4;
        dst[(long long)pl * EMBD + pc] = lds[pl][pc];
    }
}

__global__ __launch_bounds__(256) void head_k(const float* __restrict__ H0, const float* g,
                                              const float* bb, const float* cw, const float* cb,
                                              float* __restrict__ out) {
    int b = blockIdx.x, t = threadIdx.x;
    const float* x = H0 + (long long)b * NTOK * EMBD;
    float v0 = x[t], v1 = x[t + 256];
    float mu = block_sum256(v0 + v1) * (1.f / EMBD);
    float d0 = v0 - mu, d1 = v1 - mu;
    float var = block_sum256(d0 * d0 + d1 * d1) * (1.f / EMBD);
    float rs = 1.f / sqrtf(var + 1e-5f);
    float y0 = d0 * rs * g[t] + bb[t];
    float y1 = d1 * rs * g[t + 256] + bb[t + 256];
    float s = block_sum256(y0 * cw[t] + y1 * cw[t + 256]);
    if (t == 0) out[b] = s + cb[0];
}

// ---------------- host orchestration ----------------
extern "C" void kernel_launch(void* const* d_in, const int* in_sizes, int n_in,
                              void* d_out, int out_size, void* d_ws, size_t ws_size,
                              hipStream_t stream) {
    (void)in_sizes; (void)n_in; (void)out_size; (void)ws_size;
    const float* X        = (const float*)d_in[0];
    const float* few_w    = (const float*)d_in[1];
    const float* few_b    = (const float*)d_in[2];
    const float* cls_tok  = (const float*)d_in[3];
    const float* ln_g[2]  = {(const float*)d_in[4],  (const float*)d_in[10]};
    const float* ln_b[2]  = {(const float*)d_in[5],  (const float*)d_in[11]};
    const float* qkv_w[2] = {(const float*)d_in[6],  (const float*)d_in[12]};
    const float* out_w[2] = {(const float*)d_in[7],  (const float*)d_in[13]};
    const float* out_b[2] = {(const float*)d_in[8],  (const float*)d_in[14]};
    const float* res_k[2] = {(const float*)d_in[9],  (const float*)d_in[15]};
    const float* k7 = (const float*)d_in[16]; const float* b7 = (const float*)d_in[17];
    const float* k5 = (const float*)d_in[18]; const float* b5 = (const float*)d_in[19];
    const float* k3 = (const float*)d_in[20]; const float* b3 = (const float*)d_in[21];
    const float* norm_g = (const float*)d_in[22]; const float* norm_b = (const float*)d_in[23];
    const float* cls_w  = (const float*)d_in[24]; const float* cls_b  = (const float*)d_in[25];
    float* out = (float*)d_out;

    // workspace layout (floats)
    float* ws  = (float*)d_ws;
    float* H0  = ws;                         // 8*4097*512
    float* LNH = H0  + 16781312LL;           // 8*4352*512   (also ATT2)
    float* QKV = LNH + 17825792LL;           // 8*4352*1536  (also PPEG Tpad/Tout)
    float* A3  = QKV + 53477376LL;           // 32*256*4352  (also A1 / pinv temps / WSUM)
    float* QL  = A3  + 35651584LL;
    float* KL  = QL  + 1048576LL;
    float* A2  = KL  + 1048576LL;
    float* KV  = A2  + 2097152LL;
    float* ZKV = KV  + 1048576LL;
    float* RED = ZKV + 1048576LL;
    float* Zb0 = A3;                 // pinv temps overlay A3 (dead after KV gemm)
    float* Zb1 = A3 + 2097152LL;
    float* XZm = A3 + 4194304LL;
    float* Tpad = QKV;               // PPEG buffers overlay QKV (dead after resconv)
    float* Tout = QKV + TPAD_FLOATS;
    float* WSUM = A3;                // A3 free between layers

    auto gemmx = [&](const float* A, long long As1, long long As2, int Adiv, int Am, int Arow,
                     const float* Bm, long long Bs1, long long Bs2, int Bdiv, int Bk, int Bn,
                     float* C, long long Cs1, long long Cs2, int Cdiv, int Cm, int Crow,
                     int M, int N, int K, int nb, float alpha, int accum, const float* bias,
                     float bdiagc, int btrans, float cdiagc, int ctrans) {
        GemmP p;
        p.A = A; p.B = Bm; p.C = C; p.bias = bias;
        p.As1 = As1; p.As2 = As2; p.Bs1 = Bs1; p.Bs2 = Bs2; p.Cs1 = Cs1; p.Cs2 = Cs2;
        p.Adiv = Adiv; p.Bdiv = Bdiv; p.Cdiv = Cdiv;
        p.Am = Am; p.Bk = Bk; p.Bn = Bn; p.Cm = Cm; p.Arow = Arow; p.Crow = Crow;
        p.M = M; p.N = N; p.K = K; p.nb = nb; p.alpha = alpha; p.accum = accum;
        p.bdiagc = bdiagc; p.btrans = btrans; p.cdiagc = cdiagc; p.ctrans = ctrans;
        dim3 grid(N / 64, (M + 63) / 64, nb);
        gemm_k<<<grid, 256, 0, stream>>>(p);
    };
    auto gemm = [&](const float* A, long long As1, long long As2, int Adiv, int Am, int Arow,
                    const float* Bm, long long Bs1, long long Bs2, int Bdiv, int Bk, int Bn,
                    float* C, long long Cs1, long long Cs2, int Cdiv, int Cm, int Crow,
                    int M, int N, int K, int nb, float alpha, int accum, const float* bias) {
        gemmx(A, As1, As2, Adiv, Am, Arow, Bm, Bs1, Bs2, Bdiv, Bk, Bn,
              C, Cs1, Cs2, Cdiv, Cm, Crow, M, N, K, nb, alpha, accum, bias, 0.f, 0, 0.f, 0);
    };

    // ---- stem: cls token + few-shot linear ----
    cls_set_k<<<16, 256, 0, stream>>>(H0, cls_tok);
    gemm(X, 4194304LL, 0, 1, 1024, 0,
         few_w, 0, 0, 1, 512, 1,
         H0, 2097664LL, 0, 1, 512, 1,
         4096, 512, 1024, BATCH, 1.f, 0, few_b);

    for (int L = 0; L < 2; ++L) {
        ln_pad_k<<<dim3(NP, BATCH), 256, 0, stream>>>(H0, LNH, ln_g[L], ln_b[L]);
        gemm(LNH, 0, 0, 1, 512, 0,
             qkv_w[L], 0, 0, 1, 1536, 1,
             QKV, 0, 0, 1, 1536, 0,
             BATCH * NP, 1536, 512, 1, 1.f, 0, nullptr);
        landmark_k<<<4096, 256, 0, stream>>>(QKV, QL, KL);
        // a2 = softmax(SCALE * QL @ KL^T)
        gemm(QL, 32768LL, 0, 1, 128, 0,
             KL, 32768LL, 0, 1, 1, 128,
             A2, 65536LL, 0, 1, 256, 0,
             256, 256, 128, 32, SCALE_F, 0, nullptr);
        softmax256_k<<<2048, 256, 0, stream>>>(A2);
        // a3 = softmax(SCALE * QL @ K^T)
        gemm(QL, 32768LL, 0, 1, 128, 0,
             QKV + 512, 6680064LL, 128LL, 4, 1, 1536,
             A3, 1114112LL, 0, 1, 4352, 0,
             256, 4352, 128, 32, SCALE_F, 0, nullptr);
        softmax_k<<<8192, 256, 0, stream>>>(A3, 4352);
        // KV = a3 @ V
        gemm(A3, 1114112LL, 0, 1, 4352, 0,
             QKV + 1024, 6680064LL, 128LL, 4, 1536, 1,
             KV, 32768LL, 0, 1, 128, 0,
             256, 128, 4352, 32, 1.f, 0, nullptr);
        // pinv(a2): global-scalar init + 6 Newton iterations (4 fused gemms each)
        pinv_absmax_k<<<32, 256, 0, stream>>>(A2, RED);
        pinv_scalar_k<<<1, 1, 0, stream>>>(RED, RED + 64);
        pinv_tinit_k<<<8192, 256, 0, stream>>>(A2, RED + 64, Zb0);
        float* zc = Zb0; float* zn = Zb1;
        for (int it = 0; it < 6; ++it) {
            float* U1 = A3 + 6291456LL;
            float* U2 = A3 + 8388608LL;
            gemm(A2, 65536LL, 0, 1, 256, 0, zc, 65536LL, 0, 1, 256, 1,
                 XZm, 65536LL, 0, 1, 256, 0, 256, 256, 256, 32, 1.f, 0, nullptr);
            gemmx(XZm, 65536LL, 0, 1, 256, 0, XZm, 65536LL, 0, 1, 256, 1,
                  U1, 65536LL, 0, 1, 256, 0, 256, 256, 256, 32, 1.f, 0, nullptr,
                  7.f, 1, 15.f, 1);
            gemmx(XZm, 65536LL, 0, 1, 256, 0, U1, 65536LL, 0, 1, 256, 1,
                  U2, 65536LL, 0, 1, 256, 0, 256, 256, 256, 32, 1.f, 0, nullptr,
                  0.f, 0, 13.f, 1);
            gemm(zc, 65536LL, 0, 1, 256, 0, U2, 65536LL, 0, 1, 256, 1,
                 zn, 65536LL, 0, 1, 256, 0, 256, 256, 256, 32, 0.25f, 0, nullptr);
            float* t2 = zc; zc = zn; zn = t2;
        }
        // ZKV = pinv @ KV
        gemm(zc, 65536LL, 0, 1, 256, 0,
             KV, 32768LL, 0, 1, 128, 1,
             ZKV, 32768LL, 0, 1, 128, 0,
             256, 128, 256, 32, 1.f, 0, nullptr);
        // a1 = softmax(SCALE * Q @ KL^T)
        gemm(QKV, 6680064LL, 128LL, 4, 1536, 0,
             KL, 32768LL, 0, 1, 1, 128,
             A3, 1114112LL, 0, 1, 256, 0,
             4352, 256, 128, 32, SCALE_F, 0, nullptr);
        softmax256_k<<<34816, 256, 0, stream>>>(A3);
        // ATT2 = a1 @ ZKV
        gemm(A3, 1114112LL, 0, 1, 256, 0,
             ZKV, 32768LL, 0, 1, 128, 1,
             LNH, 2228224LL, 128LL, 4, 512, 0,
             4352, 128, 256, 32, 1.f, 0, nullptr);
        resconv_k<<<65552, 256, 0, stream>>>(QKV, res_k[L], LNH);
        // H0 += ATT2[PADR:] @ out_w + out_b
        gemm(LNH, 2228224LL, 0, 1, 512, PADR,
             out_w[L], 0, 0, 1, 512, 1,
             H0, 2097664LL, 0, 1, 512, 0,
             NTOK, 512, 512, BATCH, 1.f, 1, out_b[L]);

        if (L == 0) {
            hipMemsetAsync(Tpad, 0, TPAD_FLOATS * sizeof(float), stream);
            wsum_k<<<101, 256, 0, stream>>>(k7, k5, k3, b7, b5, b3, WSUM);
            tin_k<<<dim3(64, 8, 8), 256, 0, stream>>>(H0, Tpad);
            conv7_k<<<4096, 256, 0, stream>>>(Tpad, WSUM, Tout);
            tout_k<<<dim3(64, 8, 8), 256, 0, stream>>>(Tout, H0);
        }
    }

    head_k<<<BATCH, 256, 0, stream>>>(H0, norm_g, norm_b, cls_w, cls_b, out);
}